// Round 1
// baseline (368.933 us; speedup 1.0000x reference)
//
#include <hip/hip_runtime.h>
#include <cstdint>
#include <cstddef>

#define N_NODES 4096
#define NWORDS  64          // 4096 bits / 64
#define E_EDGES 131072
#define D_FEAT  256
#define D4      (D_FEAT/4)  // 64 float4 per row

typedef unsigned long long u64;

// ---------------------------------------------------------------- scatter
__global__ __launch_bounds__(256) void k_scatter(const int* __restrict__ ei,
                                                 u64* __restrict__ Ab, u64* __restrict__ Atb) {
    int e = blockIdx.x * 256 + threadIdx.x;
    if (e >= E_EDGES) return;
    int r = ei[e];
    int c = ei[E_EDGES + e];
    atomicOr(&Ab [(size_t)r * NWORDS + (c >> 6)], 1ull << (c & 63));
    atomicOr(&Atb[(size_t)c * NWORDS + (r >> 6)], 1ull << (r & 63));
}

// ---------------------------------------------------------------- degrees (wave per node)
__global__ __launch_bounds__(256) void k_degrees(const u64* __restrict__ Ab, const u64* __restrict__ Atb,
                                                 float* __restrict__ dout, float* __restrict__ din) {
    int wid  = (blockIdx.x * blockDim.x + threadIdx.x) >> 6;
    int lane = threadIdx.x & 63;
    if (wid >= N_NODES) return;
    int c1 = __popcll(Ab [(size_t)wid * NWORDS + lane]);
    int c2 = __popcll(Atb[(size_t)wid * NWORDS + lane]);
    for (int off = 32; off; off >>= 1) {
        c1 += __shfl_down(c1, off);
        c2 += __shfl_down(c2, off);
    }
    if (lane == 0) { dout[wid] = (float)c1; din[wid] = (float)c2; }
}

// ---------------------------------------------------------------- prefix sums (one block)
__global__ __launch_bounds__(1024) void k_prefix2(const float* __restrict__ dA, int* __restrict__ rpA,
                                                  const float* __restrict__ dB, int* __restrict__ rpB) {
    __shared__ int sm[1024];
    int t = threadIdx.x;
    for (int pass = 0; pass < 2; ++pass) {
        const float* d = pass ? dB : dA;
        int* rp        = pass ? rpB : rpA;
        int base = t * 4;
        int v0 = (int)d[base], v1 = (int)d[base+1], v2 = (int)d[base+2], v3 = (int)d[base+3];
        int s = v0 + v1 + v2 + v3;
        sm[t] = s;
        __syncthreads();
        for (int off = 1; off < 1024; off <<= 1) {
            int xv = (t >= off) ? sm[t - off] : 0;
            __syncthreads();
            sm[t] += xv;
            __syncthreads();
        }
        int excl = sm[t] - s;
        rp[base]   = excl;
        rp[base+1] = excl + v0;
        rp[base+2] = excl + v0 + v1;
        rp[base+3] = excl + v0 + v1 + v2;
        if (t == 1023) rp[4096] = sm[1023];
        __syncthreads();
    }
}

// ---------------------------------------------------------------- CSR fill (thread per node)
__global__ __launch_bounds__(256) void k_fill_csr(const u64* __restrict__ bits,
                                                  const int* __restrict__ rp, int* __restrict__ cols) {
    int i = blockIdx.x * blockDim.x + threadIdx.x;
    if (i >= N_NODES) return;
    int p = rp[i];
    for (int w = 0; w < NWORDS; ++w) {
        u64 b = bits[(size_t)i * NWORDS + w];
        while (b) {
            int t = __builtin_ctzll(b);
            cols[p++] = w * 64 + t;
            b &= b - 1;
        }
    }
}

// ---------------------------------------------------------------- per-edge common-neighbor counts + sums (wave per node)
// bits: succ (Ab) or pred (Atb) bitsets; dcol: d_in (out-pass) or d_out (in-pass)
__global__ __launch_bounds__(256) void k_so_edges(const u64* __restrict__ bits,
                                                  const int* __restrict__ rp, const int* __restrict__ cols,
                                                  const float* __restrict__ dcol,
                                                  float* __restrict__ ce, float* __restrict__ rfull,
                                                  float* __restrict__ rowsub, float* __restrict__ csub) {
    int wid  = (blockIdx.x * blockDim.x + threadIdx.x) >> 6;
    int lane = threadIdx.x & 63;
    if (wid >= N_NODES) return;
    u64 aw = bits[(size_t)wid * NWORDS + lane];
    int p0 = rp[wid], p1 = rp[wid + 1];
    float rf = 0.f, rs = 0.f;
    for (int p = p0; p < p1; ++p) {
        int j = cols[p];
        u64 bw = bits[(size_t)j * NWORDS + lane];
        int c = __popcll(aw & bw);
        for (int off = 32; off; off >>= 1) c += __shfl_xor(c, off);
        float cf = (j == wid) ? 0.f : (float)c;   // self-loop handled by diag term
        rf += dcol[j];
        rs += cf;
        if (lane == 0) {
            ce[p] = cf;
            if (cf != 0.f) atomicAdd(&csub[j], cf);
        }
    }
    if (lane == 0) { rfull[wid] = rf; rowsub[wid] = rs; }
}

// ---------------------------------------------------------------- scales
__global__ __launch_bounds__(256) void k_finalize(const float* __restrict__ dout, const float* __restrict__ din,
                                                  const float* __restrict__ rfo, const float* __restrict__ rso, const float* __restrict__ cso,
                                                  const float* __restrict__ rfi, const float* __restrict__ rsi, const float* __restrict__ csi,
                                                  float* __restrict__ s_do, float* __restrict__ s_di,
                                                  float* __restrict__ ro_s, float* __restrict__ co_s,
                                                  float* __restrict__ ri_s, float* __restrict__ ci_s) {
    int i = blockIdx.x * blockDim.x + threadIdx.x;
    if (i >= N_NODES) return;
    float d_o = dout[i], d_i = din[i];
    s_do[i] = d_o > 0.f ? rsqrtf(d_o) : 0.f;
    s_di[i] = d_i > 0.f ? rsqrtf(d_i) : 0.f;
    float ro = rfo[i] - d_o - rso[i];   // masked SO_out row sum
    float co = rfo[i] - d_o - cso[i];   // masked SO_out col sum (full matrix symmetric)
    float ri = rfi[i] - d_i - rsi[i];   // masked SO_in row sum
    float ci = rfi[i] - d_i - csi[i];   // masked SO_in col sum
    ro_s[i] = ro > 0.f ? rsqrtf(ro) : 0.f;
    co_s[i] = co > 0.f ? rsqrtf(co) : 0.f;
    ri_s[i] = ri > 0.f ? rsqrtf(ri) : 0.f;
    ci_s[i] = ci > 0.f ? rsqrtf(ci) : 0.f;
}

// ---------------------------------------------------------------- fused SpMM pass (wave per node, lane = float4 of features)
// Y[i]    = 0.35*srow_fo[i]*Sum_j scol_fo[j]*x[j]
//         - 0.15*srow_so[i]*( Sum_j ce[e]*scol_so[j]*x[j] + dself[i]*scol_so[i]*x[i] )
// zout[i] = Sum_j scol_z[j]*x[j]
__global__ __launch_bounds__(256) void k_fused_pass(const int* __restrict__ rp, const int* __restrict__ cols,
                                                    const float* __restrict__ ce, const float* __restrict__ x,
                                                    float* __restrict__ Y, float* __restrict__ zout,
                                                    const float* __restrict__ srow_fo, const float* __restrict__ scol_fo,
                                                    const float* __restrict__ srow_so, const float* __restrict__ scol_so,
                                                    const float* __restrict__ scol_z, const float* __restrict__ dself) {
    int wid  = (blockIdx.x * blockDim.x + threadIdx.x) >> 6;
    int lane = threadIdx.x & 63;
    if (wid >= N_NODES) return;
    const float4* x4 = (const float4*)x;
    float4 a1 = {0,0,0,0}, a2 = {0,0,0,0}, az = {0,0,0,0};
    int p0 = rp[wid], p1 = rp[wid + 1];
    for (int p = p0; p < p1; ++p) {
        int j = cols[p];
        float w1 = scol_fo[j];
        float w2 = ce[p] * scol_so[j];
        float wz = scol_z[j];
        float4 v = x4[(size_t)j * D4 + lane];
        a1.x += w1 * v.x; a1.y += w1 * v.y; a1.z += w1 * v.z; a1.w += w1 * v.w;
        a2.x += w2 * v.x; a2.y += w2 * v.y; a2.z += w2 * v.z; a2.w += w2 * v.w;
        az.x += wz * v.x; az.y += wz * v.y; az.z += wz * v.z; az.w += wz * v.w;
    }
    float wd = dself[wid] * scol_so[wid];
    float4 vi = x4[(size_t)wid * D4 + lane];
    a2.x += wd * vi.x; a2.y += wd * vi.y; a2.z += wd * vi.z; a2.w += wd * vi.w;
    float c1 = 0.35f * srow_fo[wid];
    float c2 = -0.15f * srow_so[wid];
    float4 r;
    r.x = c1 * a1.x + c2 * a2.x;
    r.y = c1 * a1.y + c2 * a2.y;
    r.z = c1 * a1.z + c2 * a2.z;
    r.w = c1 * a1.w + c2 * a2.w;
    ((float4*)Y   )[(size_t)wid * D4 + lane] = r;
    ((float4*)zout)[(size_t)wid * D4 + lane] = az;
}

// ---------------------------------------------------------------- accumulate pass: Y[i] += 0.15*srow[i]*Sum_j z[j]
__global__ __launch_bounds__(256) void k_spmm_accum(const int* __restrict__ rp, const int* __restrict__ cols,
                                                    const float* __restrict__ zin, float* __restrict__ Y,
                                                    const float* __restrict__ srow) {
    int wid  = (blockIdx.x * blockDim.x + threadIdx.x) >> 6;
    int lane = threadIdx.x & 63;
    if (wid >= N_NODES) return;
    const float4* z4 = (const float4*)zin;
    float4 a = {0,0,0,0};
    int p0 = rp[wid], p1 = rp[wid + 1];
    for (int p = p0; p < p1; ++p) {
        int j = cols[p];
        float4 v = z4[(size_t)j * D4 + lane];
        a.x += v.x; a.y += v.y; a.z += v.z; a.w += v.w;
    }
    float s = 0.15f * srow[wid];
    float4* y4 = (float4*)Y;
    float4 cur = y4[(size_t)wid * D4 + lane];
    cur.x += s * a.x; cur.y += s * a.y; cur.z += s * a.z; cur.w += s * a.w;
    y4[(size_t)wid * D4 + lane] = cur;
}

// ---------------------------------------------------------------- final GEMM: out = Ysrc@Ws^T + Ydst@Wd^T + 0.5*(bs+bd)
__global__ __launch_bounds__(256) void k_sgemm(const float* __restrict__ Ysrc, const float* __restrict__ Ydst,
                                               const float* __restrict__ Ws, const float* __restrict__ Wd,
                                               const float* __restrict__ bsrc, const float* __restrict__ bdst,
                                               float* __restrict__ out) {
    __shared__ float As[64][36];
    __shared__ float Bs[64][36];
    int tid = threadIdx.x;
    int tx = tid & 15, ty = tid >> 4;
    int row0 = blockIdx.x * 64;
    int col0 = blockIdx.y * 64;
    float acc[4][4] = {};
    for (int half = 0; half < 2; ++half) {
        const float* Y = half ? Ydst : Ysrc;
        const float* W = half ? Wd : Ws;
        for (int k0 = 0; k0 < 256; k0 += 32) {
            int lr = tid >> 2;
            int lc = (tid & 3) * 8;
            float4 a0 = *(const float4*)&Y[(size_t)(row0 + lr) * 256 + k0 + lc];
            float4 a1 = *(const float4*)&Y[(size_t)(row0 + lr) * 256 + k0 + lc + 4];
            float4 b0 = *(const float4*)&W[(size_t)(col0 + lr) * 256 + k0 + lc];
            float4 b1 = *(const float4*)&W[(size_t)(col0 + lr) * 256 + k0 + lc + 4];
            __syncthreads();
            *(float4*)&As[lr][lc]     = a0;
            *(float4*)&As[lr][lc + 4] = a1;
            *(float4*)&Bs[lr][lc]     = b0;
            *(float4*)&Bs[lr][lc + 4] = b1;
            __syncthreads();
#pragma unroll
            for (int kk = 0; kk < 32; ++kk) {
                float a[4], b[4];
#pragma unroll
                for (int r = 0; r < 4; ++r) a[r] = As[ty * 4 + r][kk];
#pragma unroll
                for (int c = 0; c < 4; ++c) b[c] = Bs[tx * 4 + c][kk];
#pragma unroll
                for (int r = 0; r < 4; ++r)
#pragma unroll
                    for (int c = 0; c < 4; ++c) acc[r][c] += a[r] * b[c];
            }
        }
    }
#pragma unroll
    for (int r = 0; r < 4; ++r) {
        int orow = row0 + ty * 4 + r;
#pragma unroll
        for (int c = 0; c < 4; ++c) {
            int ocol = col0 + tx * 4 + c;
            out[(size_t)orow * 256 + ocol] = acc[r][c] + 0.5f * (bsrc[ocol] + bdst[ocol]);
        }
    }
}

// ---------------------------------------------------------------- launch
extern "C" void kernel_launch(void* const* d_in, const int* in_sizes, int n_in,
                              void* d_out, int out_size, void* d_ws, size_t ws_size,
                              hipStream_t stream) {
    const float* x  = (const float*)d_in[0];
    const int*   ei = (const int*)  d_in[1];
    const float* Ws = (const float*)d_in[2];
    const float* bs = (const float*)d_in[3];
    const float* Wd = (const float*)d_in[4];
    const float* bd = (const float*)d_in[5];
    float* out = (float*)d_out;

    char* ws = (char*)d_ws;
    size_t off = 0;
    auto alloc = [&](size_t bytes) -> void* {
        void* p = ws + off;
        off = (off + bytes + 255) & ~(size_t)255;
        return p;
    };
    u64*   Ab      = (u64*)  alloc((size_t)N_NODES * NWORDS * 8);   // 2 MB
    u64*   Atb     = (u64*)  alloc((size_t)N_NODES * NWORDS * 8);   // 2 MB (contiguous with Ab)
    float* csub_o  = (float*)alloc(N_NODES * 4);
    float* csub_i  = (float*)alloc(N_NODES * 4);                    // contiguous with csub_o
    float* d_o     = (float*)alloc(N_NODES * 4);
    float* d_i     = (float*)alloc(N_NODES * 4);
    int*   rp_o    = (int*)  alloc((N_NODES + 1) * 4);
    int*   rp_i    = (int*)  alloc((N_NODES + 1) * 4);
    int*   col_o   = (int*)  alloc((size_t)E_EDGES * 4);
    int*   col_i   = (int*)  alloc((size_t)E_EDGES * 4);
    float* ce_o    = (float*)alloc((size_t)E_EDGES * 4);
    float* ce_i    = (float*)alloc((size_t)E_EDGES * 4);
    float* rfull_o = (float*)alloc(N_NODES * 4);
    float* rsub_o  = (float*)alloc(N_NODES * 4);
    float* rfull_i = (float*)alloc(N_NODES * 4);
    float* rsub_i  = (float*)alloc(N_NODES * 4);
    float* s_do    = (float*)alloc(N_NODES * 4);
    float* s_di    = (float*)alloc(N_NODES * 4);
    float* ro_s    = (float*)alloc(N_NODES * 4);
    float* co_s    = (float*)alloc(N_NODES * 4);
    float* ri_s    = (float*)alloc(N_NODES * 4);
    float* ci_s    = (float*)alloc(N_NODES * 4);
    float* zbuf    = (float*)alloc((size_t)N_NODES * D_FEAT * 4);   // 4 MB
    float* z2buf   = (float*)alloc((size_t)N_NODES * D_FEAT * 4);   // 4 MB
    float* Ysrc    = (float*)alloc((size_t)N_NODES * D_FEAT * 4);   // 4 MB
    float* Ydst    = (float*)alloc((size_t)N_NODES * D_FEAT * 4);   // 4 MB

    // zero bitsets (Ab+Atb contiguous) and csub arrays (contiguous)
    hipMemsetAsync(Ab, 0, (size_t)N_NODES * NWORDS * 8 * 2, stream);
    hipMemsetAsync(csub_o, 0, (size_t)N_NODES * 4 * 2, stream);

    k_scatter<<<(E_EDGES + 255) / 256, 256, 0, stream>>>(ei, Ab, Atb);
    k_degrees<<<(N_NODES * 64) / 256, 256, 0, stream>>>(Ab, Atb, d_o, d_i);
    k_prefix2<<<1, 1024, 0, stream>>>(d_o, rp_o, d_i, rp_i);
    k_fill_csr<<<(N_NODES + 255) / 256, 256, 0, stream>>>(Ab, rp_o, col_o);
    k_fill_csr<<<(N_NODES + 255) / 256, 256, 0, stream>>>(Atb, rp_i, col_i);
    // SO_out: succ-bitset intersections; rfull uses d_in. SO_in: pred-bitsets; rfull uses d_out.
    k_so_edges<<<(N_NODES * 64) / 256, 256, 0, stream>>>(Ab,  rp_o, col_o, d_i, ce_o, rfull_o, rsub_o, csub_o);
    k_so_edges<<<(N_NODES * 64) / 256, 256, 0, stream>>>(Atb, rp_i, col_i, d_o, ce_i, rfull_i, rsub_i, csub_i);
    k_finalize<<<(N_NODES + 255) / 256, 256, 0, stream>>>(d_o, d_i, rfull_o, rsub_o, csub_o,
                                                          rfull_i, rsub_i, csub_i,
                                                          s_do, s_di, ro_s, co_s, ri_s, ci_s);
    // Pass 1 (csr_out, x): Ysrc = 0.35*A_n@x - 0.15*mask-corr(SO_out);  z2 = A@(ci_s*x)
    k_fused_pass<<<(N_NODES * 64) / 256, 256, 0, stream>>>(rp_o, col_o, ce_o, x, Ysrc, z2buf,
                                                           s_do, s_di, ro_s, co_s, ci_s, d_o);
    // Pass 2 (csr_in, x): Ydst = 0.35*At_n@x - 0.15*mask-corr(SO_in);  z = At@(co_s*x)
    k_fused_pass<<<(N_NODES * 64) / 256, 256, 0, stream>>>(rp_i, col_i, ce_i, x, Ydst, zbuf,
                                                           s_di, s_do, ri_s, ci_s, co_s, d_i);
    // Pass 3: Ysrc += 0.15*ro_s*(A@z)
    k_spmm_accum<<<(N_NODES * 64) / 256, 256, 0, stream>>>(rp_o, col_o, zbuf, Ysrc, ro_s);
    // Pass 4: Ydst += 0.15*ri_s*(At@z2)
    k_spmm_accum<<<(N_NODES * 64) / 256, 256, 0, stream>>>(rp_i, col_i, z2buf, Ydst, ri_s);
    // Final: out = Ysrc@Ws^T + Ydst@Wd^T + 0.5*(bs+bd)
    k_sgemm<<<dim3(N_NODES / 64, D_FEAT / 64), 256, 0, stream>>>(Ysrc, Ydst, Ws, Wd, bs, bd, out);
}

// Round 3
// 203.671 us; speedup vs baseline: 1.8114x; 1.8114x over previous
//
#include <hip/hip_runtime.h>
#include <cstdint>
#include <cstddef>

#define N_NODES 4096
#define NWORDS  64          // 4096 bits / 64
#define E_EDGES 131072
#define D_FEAT  256
#define D4      (D_FEAT/4)  // 64 float4 per row

typedef unsigned long long u64;

// ---------------------------------------------------------------- scatter
__global__ __launch_bounds__(256) void k_scatter(const int* __restrict__ ei,
                                                 u64* __restrict__ Ab, u64* __restrict__ Atb) {
    int e = blockIdx.x * 256 + threadIdx.x;
    if (e >= E_EDGES) return;
    int r = ei[e];
    int c = ei[E_EDGES + e];
    atomicOr(&Ab [(size_t)r * NWORDS + (c >> 6)], 1ull << (c & 63));
    atomicOr(&Atb[(size_t)c * NWORDS + (r >> 6)], 1ull << (r & 63));
}

// ---------------------------------------------------------------- degrees (wave per node)
__global__ __launch_bounds__(256) void k_degrees(const u64* __restrict__ Ab, const u64* __restrict__ Atb,
                                                 float* __restrict__ dout, float* __restrict__ din) {
    int wid  = (blockIdx.x * blockDim.x + threadIdx.x) >> 6;
    int lane = threadIdx.x & 63;
    if (wid >= N_NODES) return;
    int c1 = __popcll(Ab [(size_t)wid * NWORDS + lane]);
    int c2 = __popcll(Atb[(size_t)wid * NWORDS + lane]);
    for (int off = 32; off; off >>= 1) {
        c1 += __shfl_down(c1, off);
        c2 += __shfl_down(c2, off);
    }
    if (lane == 0) { dout[wid] = (float)c1; din[wid] = (float)c2; }
}

// ---------------------------------------------------------------- prefix sums (one block)
__global__ __launch_bounds__(1024) void k_prefix2(const float* __restrict__ dA, int* __restrict__ rpA,
                                                  const float* __restrict__ dB, int* __restrict__ rpB) {
    __shared__ int sm[1024];
    int t = threadIdx.x;
    for (int pass = 0; pass < 2; ++pass) {
        const float* d = pass ? dB : dA;
        int* rp        = pass ? rpB : rpA;
        int base = t * 4;
        int v0 = (int)d[base], v1 = (int)d[base+1], v2 = (int)d[base+2], v3 = (int)d[base+3];
        int s = v0 + v1 + v2 + v3;
        sm[t] = s;
        __syncthreads();
        for (int off = 1; off < 1024; off <<= 1) {
            int xv = (t >= off) ? sm[t - off] : 0;
            __syncthreads();
            sm[t] += xv;
            __syncthreads();
        }
        int excl = sm[t] - s;
        rp[base]   = excl;
        rp[base+1] = excl + v0;
        rp[base+2] = excl + v0 + v1;
        rp[base+3] = excl + v0 + v1 + v2;
        if (t == 1023) rp[4096] = sm[1023];
        __syncthreads();
    }
}

// ---------------------------------------------------------------- CSR fill (wave per node, shfl prefix scan)
__global__ __launch_bounds__(256) void k_fill_csr(const u64* __restrict__ bits,
                                                  const int* __restrict__ rp, int* __restrict__ cols) {
    int wid  = (blockIdx.x * blockDim.x + threadIdx.x) >> 6;
    int lane = threadIdx.x & 63;
    if (wid >= N_NODES) return;
    u64 w = bits[(size_t)wid * NWORDS + lane];
    int cnt = __popcll(w);
    int inc = cnt;
    for (int off = 1; off < 64; off <<= 1) {
        int t = __shfl_up(inc, off);
        if (lane >= off) inc += t;
    }
    int pos = rp[wid] + inc - cnt;   // exclusive prefix of set-bit counts
    while (w) {
        int t = __builtin_ctzll(w);
        cols[pos++] = lane * 64 + t;
        w &= w - 1;
    }
}

// ---------------------------------------------------------------- per-edge common-neighbor counts (4 edges/wave)
// 16-lane groups: group g handles edges p0+g, p0+g+4, ...; lane s holds words 4s..4s+3.
__global__ __launch_bounds__(256) void k_so_edges(const u64* __restrict__ bits,
                                                  const int* __restrict__ rp, const int* __restrict__ cols,
                                                  const float* __restrict__ dcol,
                                                  float* __restrict__ ce, float* __restrict__ rfull,
                                                  float* __restrict__ rowsub, float* __restrict__ csub) {
    int wid  = (blockIdx.x * blockDim.x + threadIdx.x) >> 6;
    int lane = threadIdx.x & 63;
    if (wid >= N_NODES) return;
    int g = lane >> 4, s = lane & 15;
    const u64* aw = &bits[(size_t)wid * NWORDS + s * 4];
    u64 a0 = aw[0], a1 = aw[1], a2 = aw[2], a3 = aw[3];
    int p0 = rp[wid], p1 = rp[wid + 1];
    float rf = 0.f, rs = 0.f;
    for (int p = p0 + g; p < p1; p += 4) {
        int j = cols[p];
        const u64* bw = &bits[(size_t)j * NWORDS + s * 4];
        u64 b0 = bw[0], b1 = bw[1], b2 = bw[2], b3 = bw[3];
        int c = __popcll(a0 & b0) + __popcll(a1 & b1) + __popcll(a2 & b2) + __popcll(a3 & b3);
        c += __shfl_xor(c, 1);
        c += __shfl_xor(c, 2);
        c += __shfl_xor(c, 4);
        c += __shfl_xor(c, 8);
        if (s == 0) {
            float cf = (j == wid) ? 0.f : (float)c;   // self-loop handled by diag term
            ce[p] = cf;
            if (cf != 0.f) atomicAdd(&csub[j], cf);
            rs += cf;
            rf += dcol[j];
        }
    }
    rf += __shfl_xor(rf, 16); rf += __shfl_xor(rf, 32);
    rs += __shfl_xor(rs, 16); rs += __shfl_xor(rs, 32);
    if (lane == 0) { rfull[wid] = rf; rowsub[wid] = rs; }
}

// ---------------------------------------------------------------- scales
__global__ __launch_bounds__(256) void k_finalize(const float* __restrict__ dout, const float* __restrict__ din,
                                                  const float* __restrict__ rfo, const float* __restrict__ rso, const float* __restrict__ cso,
                                                  const float* __restrict__ rfi, const float* __restrict__ rsi, const float* __restrict__ csi,
                                                  float* __restrict__ s_do, float* __restrict__ s_di,
                                                  float* __restrict__ ro_s, float* __restrict__ co_s,
                                                  float* __restrict__ ri_s, float* __restrict__ ci_s) {
    int i = blockIdx.x * blockDim.x + threadIdx.x;
    if (i >= N_NODES) return;
    float d_o = dout[i], d_i = din[i];
    s_do[i] = d_o > 0.f ? rsqrtf(d_o) : 0.f;
    s_di[i] = d_i > 0.f ? rsqrtf(d_i) : 0.f;
    float ro = rfo[i] - d_o - rso[i];   // masked SO_out row sum
    float co = rfo[i] - d_o - cso[i];   // masked SO_out col sum (full matrix symmetric)
    float ri = rfi[i] - d_i - rsi[i];   // masked SO_in row sum
    float ci = rfi[i] - d_i - csi[i];   // masked SO_in col sum
    ro_s[i] = ro > 0.f ? rsqrtf(ro) : 0.f;
    co_s[i] = co > 0.f ? rsqrtf(co) : 0.f;
    ri_s[i] = ri > 0.f ? rsqrtf(ri) : 0.f;
    ci_s[i] = ci > 0.f ? rsqrtf(ci) : 0.f;
}

// ---------------------------------------------------------------- fused SpMM pass (wave per node, 4-way unrolled)
// Y[i]    = 0.35*srow_fo[i]*Sum_j scol_fo[j]*x[j]
//         - 0.15*srow_so[i]*( Sum_j ce[e]*scol_so[j]*x[j] + dself[i]*scol_so[i]*x[i] )
// zout[i] = Sum_j scol_z[j]*x[j]
__global__ __launch_bounds__(256) void k_fused_pass(const int* __restrict__ rp, const int* __restrict__ cols,
                                                    const float* __restrict__ ce, const float* __restrict__ x,
                                                    float* __restrict__ Y, float* __restrict__ zout,
                                                    const float* __restrict__ srow_fo, const float* __restrict__ scol_fo,
                                                    const float* __restrict__ srow_so, const float* __restrict__ scol_so,
                                                    const float* __restrict__ scol_z, const float* __restrict__ dself) {
    int wid  = (blockIdx.x * blockDim.x + threadIdx.x) >> 6;
    int lane = threadIdx.x & 63;
    if (wid >= N_NODES) return;
    const float4* x4 = (const float4*)x;
    float4 a1 = {0,0,0,0}, a2 = {0,0,0,0}, az = {0,0,0,0};
    int p0 = rp[wid], p1 = rp[wid + 1];
    int p = p0;
    for (; p + 4 <= p1; p += 4) {
        int j0 = cols[p], j1 = cols[p+1], j2 = cols[p+2], j3 = cols[p+3];
        float4 v0 = x4[(size_t)j0 * D4 + lane];
        float4 v1 = x4[(size_t)j1 * D4 + lane];
        float4 v2 = x4[(size_t)j2 * D4 + lane];
        float4 v3 = x4[(size_t)j3 * D4 + lane];
        float f0 = scol_fo[j0], f1 = scol_fo[j1], f2 = scol_fo[j2], f3 = scol_fo[j3];
        float s0 = ce[p]   * scol_so[j0];
        float s1 = ce[p+1] * scol_so[j1];
        float s2 = ce[p+2] * scol_so[j2];
        float s3 = ce[p+3] * scol_so[j3];
        float z0 = scol_z[j0], z1 = scol_z[j1], z2 = scol_z[j2], z3 = scol_z[j3];
        a1.x += f0*v0.x + f1*v1.x + f2*v2.x + f3*v3.x;
        a1.y += f0*v0.y + f1*v1.y + f2*v2.y + f3*v3.y;
        a1.z += f0*v0.z + f1*v1.z + f2*v2.z + f3*v3.z;
        a1.w += f0*v0.w + f1*v1.w + f2*v2.w + f3*v3.w;
        a2.x += s0*v0.x + s1*v1.x + s2*v2.x + s3*v3.x;
        a2.y += s0*v0.y + s1*v1.y + s2*v2.y + s3*v3.y;
        a2.z += s0*v0.z + s1*v1.z + s2*v2.z + s3*v3.z;
        a2.w += s0*v0.w + s1*v1.w + s2*v2.w + s3*v3.w;
        az.x += z0*v0.x + z1*v1.x + z2*v2.x + z3*v3.x;
        az.y += z0*v0.y + z1*v1.y + z2*v2.y + z3*v3.y;
        az.z += z0*v0.z + z1*v1.z + z2*v2.z + z3*v3.z;
        az.w += z0*v0.w + z1*v1.w + z2*v2.w + z3*v3.w;
    }
    for (; p < p1; ++p) {
        int j = cols[p];
        float w1 = scol_fo[j];
        float w2 = ce[p] * scol_so[j];
        float wz = scol_z[j];
        float4 v = x4[(size_t)j * D4 + lane];
        a1.x += w1 * v.x; a1.y += w1 * v.y; a1.z += w1 * v.z; a1.w += w1 * v.w;
        a2.x += w2 * v.x; a2.y += w2 * v.y; a2.z += w2 * v.z; a2.w += w2 * v.w;
        az.x += wz * v.x; az.y += wz * v.y; az.z += wz * v.z; az.w += wz * v.w;
    }
    float wd = dself[wid] * scol_so[wid];
    float4 vi = x4[(size_t)wid * D4 + lane];
    a2.x += wd * vi.x; a2.y += wd * vi.y; a2.z += wd * vi.z; a2.w += wd * vi.w;
    float c1 = 0.35f * srow_fo[wid];
    float c2 = -0.15f * srow_so[wid];
    float4 r;
    r.x = c1 * a1.x + c2 * a2.x;
    r.y = c1 * a1.y + c2 * a2.y;
    r.z = c1 * a1.z + c2 * a2.z;
    r.w = c1 * a1.w + c2 * a2.w;
    ((float4*)Y   )[(size_t)wid * D4 + lane] = r;
    ((float4*)zout)[(size_t)wid * D4 + lane] = az;
}

// ---------------------------------------------------------------- accumulate pass: Y[i] += 0.15*srow[i]*Sum_j z[j]
__global__ __launch_bounds__(256) void k_spmm_accum(const int* __restrict__ rp, const int* __restrict__ cols,
                                                    const float* __restrict__ zin, float* __restrict__ Y,
                                                    const float* __restrict__ srow) {
    int wid  = (blockIdx.x * blockDim.x + threadIdx.x) >> 6;
    int lane = threadIdx.x & 63;
    if (wid >= N_NODES) return;
    const float4* z4 = (const float4*)zin;
    float4 a = {0,0,0,0};
    int p0 = rp[wid], p1 = rp[wid + 1];
    int p = p0;
    for (; p + 4 <= p1; p += 4) {
        int j0 = cols[p], j1 = cols[p+1], j2 = cols[p+2], j3 = cols[p+3];
        float4 v0 = z4[(size_t)j0 * D4 + lane];
        float4 v1 = z4[(size_t)j1 * D4 + lane];
        float4 v2 = z4[(size_t)j2 * D4 + lane];
        float4 v3 = z4[(size_t)j3 * D4 + lane];
        a.x += v0.x + v1.x + v2.x + v3.x;
        a.y += v0.y + v1.y + v2.y + v3.y;
        a.z += v0.z + v1.z + v2.z + v3.z;
        a.w += v0.w + v1.w + v2.w + v3.w;
    }
    for (; p < p1; ++p) {
        int j = cols[p];
        float4 v = z4[(size_t)j * D4 + lane];
        a.x += v.x; a.y += v.y; a.z += v.z; a.w += v.w;
    }
    float s = 0.15f * srow[wid];
    float4* y4 = (float4*)Y;
    float4 cur = y4[(size_t)wid * D4 + lane];
    cur.x += s * a.x; cur.y += s * a.y; cur.z += s * a.z; cur.w += s * a.w;
    y4[(size_t)wid * D4 + lane] = cur;
}

// ---------------------------------------------------------------- GEMM partials: P = Y @ W^T  (one half per blockIdx.z)
// K-major LDS tiles, stride 68 floats (16B aligned rows, 4-bank row offset -> conflict-free b128 fragment reads)
__global__ __launch_bounds__(256) void k_sgemm2(const float* __restrict__ Ysrc, const float* __restrict__ Ydst,
                                                const float* __restrict__ Ws, const float* __restrict__ Wd,
                                                float* __restrict__ part0, float* __restrict__ part1) {
    const float* Y = blockIdx.z ? Ydst : Ysrc;
    const float* W = blockIdx.z ? Wd : Ws;
    float* P       = blockIdx.z ? part1 : part0;
    __shared__ float As[32][68];
    __shared__ float Bs[32][68];
    int tid = threadIdx.x;
    int tx = tid & 15, ty = tid >> 4;          // 16x16 threads, 4x4 outputs each
    int row0 = blockIdx.x * 64;
    int col0 = blockIdx.y * 64;
    int lr = tid >> 2;                          // 0..63: tile row loaded by this thread
    int lc = (tid & 3) * 8;                     // 8 consecutive k per thread
    float acc[4][4] = {};
    for (int k0 = 0; k0 < 256; k0 += 32) {
        float4 a0 = *(const float4*)&Y[(size_t)(row0 + lr) * 256 + k0 + lc];
        float4 a1 = *(const float4*)&Y[(size_t)(row0 + lr) * 256 + k0 + lc + 4];
        float4 b0 = *(const float4*)&W[(size_t)(col0 + lr) * 256 + k0 + lc];
        float4 b1 = *(const float4*)&W[(size_t)(col0 + lr) * 256 + k0 + lc + 4];
        __syncthreads();
        As[lc+0][lr] = a0.x; As[lc+1][lr] = a0.y; As[lc+2][lr] = a0.z; As[lc+3][lr] = a0.w;
        As[lc+4][lr] = a1.x; As[lc+5][lr] = a1.y; As[lc+6][lr] = a1.z; As[lc+7][lr] = a1.w;
        Bs[lc+0][lr] = b0.x; Bs[lc+1][lr] = b0.y; Bs[lc+2][lr] = b0.z; Bs[lc+3][lr] = b0.w;
        Bs[lc+4][lr] = b1.x; Bs[lc+5][lr] = b1.y; Bs[lc+6][lr] = b1.z; Bs[lc+7][lr] = b1.w;
        __syncthreads();
#pragma unroll
        for (int kk = 0; kk < 32; ++kk) {
            float4 av = *(const float4*)&As[kk][ty * 4];
            float4 bv = *(const float4*)&Bs[kk][tx * 4];
            acc[0][0] += av.x * bv.x; acc[0][1] += av.x * bv.y; acc[0][2] += av.x * bv.z; acc[0][3] += av.x * bv.w;
            acc[1][0] += av.y * bv.x; acc[1][1] += av.y * bv.y; acc[1][2] += av.y * bv.z; acc[1][3] += av.y * bv.w;
            acc[2][0] += av.z * bv.x; acc[2][1] += av.z * bv.y; acc[2][2] += av.z * bv.z; acc[2][3] += av.z * bv.w;
            acc[3][0] += av.w * bv.x; acc[3][1] += av.w * bv.y; acc[3][2] += av.w * bv.z; acc[3][3] += av.w * bv.w;
        }
    }
#pragma unroll
    for (int r = 0; r < 4; ++r) {
        int orow = row0 + ty * 4 + r;
        float4 v = { acc[r][0], acc[r][1], acc[r][2], acc[r][3] };
        *(float4*)&P[(size_t)orow * 256 + col0 + tx * 4] = v;
    }
}

// ---------------------------------------------------------------- combine: out = P0 + P1 + 0.5*(bs+bd)
__global__ __launch_bounds__(256) void k_combine(const float4* __restrict__ p0, const float4* __restrict__ p1,
                                                 const float4* __restrict__ bs4, const float4* __restrict__ bd4,
                                                 float4* __restrict__ out4) {
    int i = blockIdx.x * 256 + threadIdx.x;     // over 4096*64 float4
    float4 a = p0[i], b = p1[i];
    float4 s = bs4[i & 63], d = bd4[i & 63];
    float4 r;
    r.x = a.x + b.x + 0.5f * (s.x + d.x);
    r.y = a.y + b.y + 0.5f * (s.y + d.y);
    r.z = a.z + b.z + 0.5f * (s.z + d.z);
    r.w = a.w + b.w + 0.5f * (s.w + d.w);
    out4[i] = r;
}

// ---------------------------------------------------------------- launch
extern "C" void kernel_launch(void* const* d_in, const int* in_sizes, int n_in,
                              void* d_out, int out_size, void* d_ws, size_t ws_size,
                              hipStream_t stream) {
    const float* x  = (const float*)d_in[0];
    const int*   ei = (const int*)  d_in[1];
    const float* Ws = (const float*)d_in[2];
    const float* bs = (const float*)d_in[3];
    const float* Wd = (const float*)d_in[4];
    const float* bd = (const float*)d_in[5];
    float* out = (float*)d_out;

    char* ws = (char*)d_ws;
    size_t off = 0;
    auto alloc = [&](size_t bytes) -> void* {
        void* p = ws + off;
        off = (off + bytes + 255) & ~(size_t)255;
        return p;
    };
    u64*   Ab      = (u64*)  alloc((size_t)N_NODES * NWORDS * 8);   // 2 MB
    u64*   Atb     = (u64*)  alloc((size_t)N_NODES * NWORDS * 8);   // 2 MB (contiguous with Ab)
    float* csub_o  = (float*)alloc(N_NODES * 4);
    float* csub_i  = (float*)alloc(N_NODES * 4);                    // contiguous with csub_o
    float* d_o     = (float*)alloc(N_NODES * 4);
    float* d_i     = (float*)alloc(N_NODES * 4);
    int*   rp_o    = (int*)  alloc((N_NODES + 1) * 4);
    int*   rp_i    = (int*)  alloc((N_NODES + 1) * 4);
    int*   col_o   = (int*)  alloc((size_t)E_EDGES * 4);
    int*   col_i   = (int*)  alloc((size_t)E_EDGES * 4);
    float* ce_o    = (float*)alloc((size_t)E_EDGES * 4);
    float* ce_i    = (float*)alloc((size_t)E_EDGES * 4);
    float* rfull_o = (float*)alloc(N_NODES * 4);
    float* rsub_o  = (float*)alloc(N_NODES * 4);
    float* rfull_i = (float*)alloc(N_NODES * 4);
    float* rsub_i  = (float*)alloc(N_NODES * 4);
    float* s_do    = (float*)alloc(N_NODES * 4);
    float* s_di    = (float*)alloc(N_NODES * 4);
    float* ro_s    = (float*)alloc(N_NODES * 4);
    float* co_s    = (float*)alloc(N_NODES * 4);
    float* ri_s    = (float*)alloc(N_NODES * 4);
    float* ci_s    = (float*)alloc(N_NODES * 4);
    float* zbuf    = (float*)alloc((size_t)N_NODES * D_FEAT * 4);   // 4 MB
    float* z2buf   = (float*)alloc((size_t)N_NODES * D_FEAT * 4);   // 4 MB
    float* Ysrc    = (float*)alloc((size_t)N_NODES * D_FEAT * 4);   // 4 MB
    float* Ydst    = (float*)alloc((size_t)N_NODES * D_FEAT * 4);   // 4 MB
    float* part0   = (float*)alloc((size_t)N_NODES * D_FEAT * 4);   // 4 MB
    float* part1   = (float*)alloc((size_t)N_NODES * D_FEAT * 4);   // 4 MB

    // zero bitsets (Ab+Atb contiguous) and csub arrays (contiguous)
    hipMemsetAsync(Ab, 0, (size_t)N_NODES * NWORDS * 8 * 2, stream);
    hipMemsetAsync(csub_o, 0, (size_t)N_NODES * 4 * 2, stream);

    k_scatter<<<(E_EDGES + 255) / 256, 256, 0, stream>>>(ei, Ab, Atb);
    k_degrees<<<(N_NODES * 64) / 256, 256, 0, stream>>>(Ab, Atb, d_o, d_i);
    k_prefix2<<<1, 1024, 0, stream>>>(d_o, rp_o, d_i, rp_i);
    k_fill_csr<<<(N_NODES * 64) / 256, 256, 0, stream>>>(Ab, rp_o, col_o);
    k_fill_csr<<<(N_NODES * 64) / 256, 256, 0, stream>>>(Atb, rp_i, col_i);
    // SO_out: succ-bitset intersections; rfull uses d_in. SO_in: pred-bitsets; rfull uses d_out.
    k_so_edges<<<(N_NODES * 64) / 256, 256, 0, stream>>>(Ab,  rp_o, col_o, d_i, ce_o, rfull_o, rsub_o, csub_o);
    k_so_edges<<<(N_NODES * 64) / 256, 256, 0, stream>>>(Atb, rp_i, col_i, d_o, ce_i, rfull_i, rsub_i, csub_i);
    k_finalize<<<(N_NODES + 255) / 256, 256, 0, stream>>>(d_o, d_i, rfull_o, rsub_o, csub_o,
                                                          rfull_i, rsub_i, csub_i,
                                                          s_do, s_di, ro_s, co_s, ri_s, ci_s);
    // Pass 1 (csr_out, x): Ysrc = 0.35*A_n@x - 0.15*mask-corr(SO_out);  z2 = A@(ci_s*x)
    k_fused_pass<<<(N_NODES * 64) / 256, 256, 0, stream>>>(rp_o, col_o, ce_o, x, Ysrc, z2buf,
                                                           s_do, s_di, ro_s, co_s, ci_s, d_o);
    // Pass 2 (csr_in, x): Ydst = 0.35*At_n@x - 0.15*mask-corr(SO_in);  z = At@(co_s*x)
    k_fused_pass<<<(N_NODES * 64) / 256, 256, 0, stream>>>(rp_i, col_i, ce_i, x, Ydst, zbuf,
                                                           s_di, s_do, ri_s, ci_s, co_s, d_i);
    // Pass 3: Ysrc += 0.15*ro_s*(A@z)
    k_spmm_accum<<<(N_NODES * 64) / 256, 256, 0, stream>>>(rp_o, col_o, zbuf, Ysrc, ro_s);
    // Pass 4: Ydst += 0.15*ri_s*(At@z2)
    k_spmm_accum<<<(N_NODES * 64) / 256, 256, 0, stream>>>(rp_i, col_i, z2buf, Ydst, ri_s);
    // Final GEMM halves then combine with bias
    k_sgemm2<<<dim3(N_NODES / 64, D_FEAT / 64, 2), 256, 0, stream>>>(Ysrc, Ydst, Ws, Wd, part0, part1);
    k_combine<<<(N_NODES * D_FEAT / 4) / 256, 256, 0, stream>>>((const float4*)part0, (const float4*)part1,
                                                                (const float4*)bs, (const float4*)bd,
                                                                (float4*)out);
}

// Round 5
// 182.321 us; speedup vs baseline: 2.0235x; 1.1171x over previous
//
#include <hip/hip_runtime.h>
#include <cstdint>
#include <cstddef>

#define N_NODES 4096
#define NWORDS  64          // 4096 bits / 64
#define E_EDGES 131072
#define D_FEAT  256
#define D4      (D_FEAT/4)  // 64 float4 per row

typedef unsigned long long u64;

// ---------------------------------------------------------------- scatter
__global__ __launch_bounds__(256) void k_scatter(const int* __restrict__ ei,
                                                 u64* __restrict__ Ab, u64* __restrict__ Atb) {
    int e = blockIdx.x * 256 + threadIdx.x;
    if (e >= E_EDGES) return;
    int r = ei[e];
    int c = ei[E_EDGES + e];
    atomicOr(&Ab [(size_t)r * NWORDS + (c >> 6)], 1ull << (c & 63));
    atomicOr(&Atb[(size_t)c * NWORDS + (r >> 6)], 1ull << (r & 63));
}

// ---------------------------------------------------------------- degrees (wave per node)
__global__ __launch_bounds__(256) void k_degrees(const u64* __restrict__ Ab, const u64* __restrict__ Atb,
                                                 float* __restrict__ dout, float* __restrict__ din) {
    int wid  = (blockIdx.x * blockDim.x + threadIdx.x) >> 6;
    int lane = threadIdx.x & 63;
    if (wid >= N_NODES) return;
    int c1 = __popcll(Ab [(size_t)wid * NWORDS + lane]);
    int c2 = __popcll(Atb[(size_t)wid * NWORDS + lane]);
    for (int off = 32; off; off >>= 1) {
        c1 += __shfl_down(c1, off);
        c2 += __shfl_down(c2, off);
    }
    if (lane == 0) { dout[wid] = (float)c1; din[wid] = (float)c2; }
}

// ---------------------------------------------------------------- prefix sums (one block, wave-scan: 3 barriers/pass)
__global__ __launch_bounds__(1024) void k_prefix2(const float* __restrict__ dA, int* __restrict__ rpA,
                                                  const float* __restrict__ dB, int* __restrict__ rpB) {
    __shared__ int smw[16];
    int t = threadIdx.x;
    int lane = t & 63, w = t >> 6;              // 16 waves
    for (int pass = 0; pass < 2; ++pass) {
        const float* d = pass ? dB : dA;
        int* rp        = pass ? rpB : rpA;
        int base = t * 4;
        int v0 = (int)d[base], v1 = (int)d[base+1], v2 = (int)d[base+2], v3 = (int)d[base+3];
        int s = v0 + v1 + v2 + v3;
        int inc = s;                            // wave-level inclusive scan of thread sums
        for (int off = 1; off < 64; off <<= 1) {
            int tt = __shfl_up(inc, off);
            if (lane >= off) inc += tt;
        }
        if (lane == 63) smw[w] = inc;
        __syncthreads();
        if (w == 0 && lane < 16) {              // scan the 16 wave totals
            int xv = smw[lane];
            for (int off = 1; off < 16; off <<= 1) {
                int tt = __shfl_up(xv, off);
                if (lane >= off) xv += tt;
            }
            smw[lane] = xv;                     // inclusive wave-total scan
        }
        __syncthreads();
        int woff = (w == 0) ? 0 : smw[w - 1];
        int excl = woff + inc - s;              // exclusive prefix for this thread's 4 values
        rp[base]   = excl;
        rp[base+1] = excl + v0;
        rp[base+2] = excl + v0 + v1;
        rp[base+3] = excl + v0 + v1 + v2;
        if (t == 1023) rp[4096] = smw[15];
        __syncthreads();                        // protect smw before next pass
    }
}

// ---------------------------------------------------------------- CSR fill, both directions (wave per node)
__global__ __launch_bounds__(256) void k_fill_csr2(const u64* __restrict__ Ab, const int* __restrict__ rp_o, int* __restrict__ col_o,
                                                   const u64* __restrict__ Atb, const int* __restrict__ rp_i, int* __restrict__ col_i) {
    int gw   = (blockIdx.x * blockDim.x + threadIdx.x) >> 6;
    int lane = threadIdx.x & 63;
    if (gw >= 2 * N_NODES) return;
    int half = gw >= N_NODES;
    int wid  = half ? gw - N_NODES : gw;
    const u64* bits = half ? Atb : Ab;
    const int* rp   = half ? rp_i : rp_o;
    int*       cols = half ? col_i : col_o;
    u64 wv = bits[(size_t)wid * NWORDS + lane];
    int cnt = __popcll(wv);
    int inc = cnt;
    for (int off = 1; off < 64; off <<= 1) {
        int t = __shfl_up(inc, off);
        if (lane >= off) inc += t;
    }
    int pos = rp[wid] + inc - cnt;   // exclusive prefix of set-bit counts
    while (wv) {
        int t = __builtin_ctzll(wv);
        cols[pos++] = lane * 64 + t;
        wv &= wv - 1;
    }
}

// ---------------------------------------------------------------- per-edge common-neighbor counts, both directions (4 edges/wave)
// 16-lane groups: group g handles edges p0+g, p0+g+4, ...; lane s holds words 4s..4s+3.
__global__ __launch_bounds__(256) void k_so_edges2(const u64* __restrict__ Ab,  const int* __restrict__ rp_o, const int* __restrict__ col_o,
                                                   const float* __restrict__ d_i_arr, float* __restrict__ ce_o, float* __restrict__ rfull_o,
                                                   float* __restrict__ rsub_o, float* __restrict__ csub_o,
                                                   const u64* __restrict__ Atb, const int* __restrict__ rp_i, const int* __restrict__ col_i,
                                                   const float* __restrict__ d_o_arr, float* __restrict__ ce_i, float* __restrict__ rfull_i,
                                                   float* __restrict__ rsub_i, float* __restrict__ csub_i) {
    int gw   = (blockIdx.x * blockDim.x + threadIdx.x) >> 6;
    int lane = threadIdx.x & 63;
    if (gw >= 2 * N_NODES) return;
    int half = gw >= N_NODES;
    int wid  = half ? gw - N_NODES : gw;
    const u64*   bits  = half ? Atb     : Ab;
    const int*   rp    = half ? rp_i    : rp_o;
    const int*   cols  = half ? col_i   : col_o;
    const float* dcol  = half ? d_o_arr : d_i_arr;
    float*       ce    = half ? ce_i    : ce_o;
    float*       rfull = half ? rfull_i : rfull_o;
    float*       rsub  = half ? rsub_i  : rsub_o;
    float*       csub  = half ? csub_i  : csub_o;
    int g = lane >> 4, s = lane & 15;
    const u64* aw = &bits[(size_t)wid * NWORDS + s * 4];
    u64 a0 = aw[0], a1 = aw[1], a2 = aw[2], a3 = aw[3];
    int p0 = rp[wid], p1 = rp[wid + 1];
    float rf = 0.f, rs = 0.f;
    for (int p = p0 + g; p < p1; p += 4) {
        int j = cols[p];
        const u64* bw = &bits[(size_t)j * NWORDS + s * 4];
        u64 b0 = bw[0], b1 = bw[1], b2 = bw[2], b3 = bw[3];
        int c = __popcll(a0 & b0) + __popcll(a1 & b1) + __popcll(a2 & b2) + __popcll(a3 & b3);
        c += __shfl_xor(c, 1);
        c += __shfl_xor(c, 2);
        c += __shfl_xor(c, 4);
        c += __shfl_xor(c, 8);
        if (s == 0) {
            float cf = (j == wid) ? 0.f : (float)c;   // self-loop handled by diag term
            ce[p] = cf;
            if (cf != 0.f) atomicAdd(&csub[j], cf);
            rs += cf;
            rf += dcol[j];
        }
    }
    rf += __shfl_xor(rf, 16); rf += __shfl_xor(rf, 32);
    rs += __shfl_xor(rs, 16); rs += __shfl_xor(rs, 32);
    if (lane == 0) { rfull[wid] = rf; rsub[wid] = rs; }
}

// ---------------------------------------------------------------- scales
__global__ __launch_bounds__(256) void k_finalize(const float* __restrict__ dout, const float* __restrict__ din,
                                                  const float* __restrict__ rfo, const float* __restrict__ rso, const float* __restrict__ cso,
                                                  const float* __restrict__ rfi, const float* __restrict__ rsi, const float* __restrict__ csi,
                                                  float* __restrict__ s_do, float* __restrict__ s_di,
                                                  float* __restrict__ ro_s, float* __restrict__ co_s,
                                                  float* __restrict__ ri_s, float* __restrict__ ci_s) {
    int i = blockIdx.x * blockDim.x + threadIdx.x;
    if (i >= N_NODES) return;
    float d_o = dout[i], d_i = din[i];
    s_do[i] = d_o > 0.f ? rsqrtf(d_o) : 0.f;
    s_di[i] = d_i > 0.f ? rsqrtf(d_i) : 0.f;
    float ro = rfo[i] - d_o - rso[i];   // masked SO_out row sum
    float co = rfo[i] - d_o - cso[i];   // masked SO_out col sum (full matrix symmetric)
    float ri = rfi[i] - d_i - rsi[i];   // masked SO_in row sum
    float ci = rfi[i] - d_i - csi[i];   // masked SO_in col sum
    ro_s[i] = ro > 0.f ? rsqrtf(ro) : 0.f;
    co_s[i] = co > 0.f ? rsqrtf(co) : 0.f;
    ri_s[i] = ri > 0.f ? rsqrtf(ri) : 0.f;
    ci_s[i] = ci > 0.f ? rsqrtf(ci) : 0.f;
}

// ---------------------------------------------------------------- pass A (csr_in): Ydst partial + z
// Ydst[i] = 0.35*s_di[i]*Sum_j s_do[j]*x[j] - 0.15*ri_s[i]*( Sum_j ce*ci_s[j]*x[j] + d_i[i]*ci_s[i]*x[i] )
// z[i]    = Sum_j co_s[j]*x[j]
__global__ __launch_bounds__(256) void k_fused_pass(const int* __restrict__ rp, const int* __restrict__ cols,
                                                    const float* __restrict__ ce, const float* __restrict__ x,
                                                    float* __restrict__ Y, float* __restrict__ zout,
                                                    const float* __restrict__ srow_fo, const float* __restrict__ scol_fo,
                                                    const float* __restrict__ srow_so, const float* __restrict__ scol_so,
                                                    const float* __restrict__ scol_z, const float* __restrict__ dself) {
    int wid  = (blockIdx.x * blockDim.x + threadIdx.x) >> 6;
    int lane = threadIdx.x & 63;
    if (wid >= N_NODES) return;
    const float4* x4 = (const float4*)x;
    float4 a1 = {0,0,0,0}, a2 = {0,0,0,0}, az = {0,0,0,0};
    int p0 = rp[wid], p1 = rp[wid + 1];
    int p = p0;
    for (; p + 4 <= p1; p += 4) {
        int j0 = cols[p], j1 = cols[p+1], j2 = cols[p+2], j3 = cols[p+3];
        float4 v0 = x4[(size_t)j0 * D4 + lane];
        float4 v1 = x4[(size_t)j1 * D4 + lane];
        float4 v2 = x4[(size_t)j2 * D4 + lane];
        float4 v3 = x4[(size_t)j3 * D4 + lane];
        float f0 = scol_fo[j0], f1 = scol_fo[j1], f2 = scol_fo[j2], f3 = scol_fo[j3];
        float s0 = ce[p]   * scol_so[j0];
        float s1 = ce[p+1] * scol_so[j1];
        float s2 = ce[p+2] * scol_so[j2];
        float s3 = ce[p+3] * scol_so[j3];
        float z0 = scol_z[j0], z1 = scol_z[j1], z2 = scol_z[j2], z3 = scol_z[j3];
        a1.x += f0*v0.x + f1*v1.x + f2*v2.x + f3*v3.x;
        a1.y += f0*v0.y + f1*v1.y + f2*v2.y + f3*v3.y;
        a1.z += f0*v0.z + f1*v1.z + f2*v2.z + f3*v3.z;
        a1.w += f0*v0.w + f1*v1.w + f2*v2.w + f3*v3.w;
        a2.x += s0*v0.x + s1*v1.x + s2*v2.x + s3*v3.x;
        a2.y += s0*v0.y + s1*v1.y + s2*v2.y + s3*v3.y;
        a2.z += s0*v0.z + s1*v1.z + s2*v2.z + s3*v3.z;
        a2.w += s0*v0.w + s1*v1.w + s2*v2.w + s3*v3.w;
        az.x += z0*v0.x + z1*v1.x + z2*v2.x + z3*v3.x;
        az.y += z0*v0.y + z1*v1.y + z2*v2.y + z3*v3.y;
        az.z += z0*v0.z + z1*v1.z + z2*v2.z + z3*v3.z;
        az.w += z0*v0.w + z1*v1.w + z2*v2.w + z3*v3.w;
    }
    for (; p < p1; ++p) {
        int j = cols[p];
        float w1 = scol_fo[j];
        float w2 = ce[p] * scol_so[j];
        float wz = scol_z[j];
        float4 v = x4[(size_t)j * D4 + lane];
        a1.x += w1 * v.x; a1.y += w1 * v.y; a1.z += w1 * v.z; a1.w += w1 * v.w;
        a2.x += w2 * v.x; a2.y += w2 * v.y; a2.z += w2 * v.z; a2.w += w2 * v.w;
        az.x += wz * v.x; az.y += wz * v.y; az.z += wz * v.z; az.w += wz * v.w;
    }
    float wd = dself[wid] * scol_so[wid];
    float4 vi = x4[(size_t)wid * D4 + lane];
    a2.x += wd * vi.x; a2.y += wd * vi.y; a2.z += wd * vi.z; a2.w += wd * vi.w;
    float c1 = 0.35f * srow_fo[wid];
    float c2 = -0.15f * srow_so[wid];
    float4 r;
    r.x = c1 * a1.x + c2 * a2.x;
    r.y = c1 * a1.y + c2 * a2.y;
    r.z = c1 * a1.z + c2 * a2.z;
    r.w = c1 * a1.w + c2 * a2.w;
    ((float4*)Y   )[(size_t)wid * D4 + lane] = r;
    ((float4*)zout)[(size_t)wid * D4 + lane] = az;
}

// ---------------------------------------------------------------- pass B (csr_out, fused old pass1+pass3): full Ysrc + z2
// Ysrc[i] = 0.35*s_do[i]*Sum_j s_di[j]*x[j]
//         + 0.15*ro_s[i]*( Sum_j z[j]  -  Sum_j ce*co_s[j]*x[j] - d_o[i]*co_s[i]*x[i] )
// z2[i]   = Sum_j ci_s[j]*x[j]
__global__ __launch_bounds__(256) void k_pass_b(const int* __restrict__ rp, const int* __restrict__ cols,
                                                const float* __restrict__ ce, const float* __restrict__ x,
                                                const float* __restrict__ zin,
                                                float* __restrict__ Y, float* __restrict__ z2out,
                                                const float* __restrict__ s_do, const float* __restrict__ s_di,
                                                const float* __restrict__ ro_s, const float* __restrict__ co_s,
                                                const float* __restrict__ ci_s, const float* __restrict__ d_o) {
    int wid  = (blockIdx.x * blockDim.x + threadIdx.x) >> 6;
    int lane = threadIdx.x & 63;
    if (wid >= N_NODES) return;
    const float4* x4 = (const float4*)x;
    const float4* z4 = (const float4*)zin;
    float4 a1 = {0,0,0,0}, a2 = {0,0,0,0}, az = {0,0,0,0}, a3 = {0,0,0,0};
    int p0 = rp[wid], p1 = rp[wid + 1];
    int p = p0;
    for (; p + 2 <= p1; p += 2) {
        int j0 = cols[p], j1 = cols[p+1];
        float4 v0 = x4[(size_t)j0 * D4 + lane];
        float4 v1 = x4[(size_t)j1 * D4 + lane];
        float4 u0 = z4[(size_t)j0 * D4 + lane];
        float4 u1 = z4[(size_t)j1 * D4 + lane];
        float f0 = s_di[j0], f1 = s_di[j1];
        float s0 = ce[p]   * co_s[j0];
        float s1 = ce[p+1] * co_s[j1];
        float w0 = ci_s[j0], w1 = ci_s[j1];
        a1.x += f0*v0.x + f1*v1.x;  a1.y += f0*v0.y + f1*v1.y;
        a1.z += f0*v0.z + f1*v1.z;  a1.w += f0*v0.w + f1*v1.w;
        a2.x += s0*v0.x + s1*v1.x;  a2.y += s0*v0.y + s1*v1.y;
        a2.z += s0*v0.z + s1*v1.z;  a2.w += s0*v0.w + s1*v1.w;
        az.x += w0*v0.x + w1*v1.x;  az.y += w0*v0.y + w1*v1.y;
        az.z += w0*v0.z + w1*v1.z;  az.w += w0*v0.w + w1*v1.w;
        a3.x += u0.x + u1.x;  a3.y += u0.y + u1.y;
        a3.z += u0.z + u1.z;  a3.w += u0.w + u1.w;
    }
    for (; p < p1; ++p) {
        int j = cols[p];
        float4 v = x4[(size_t)j * D4 + lane];
        float4 u = z4[(size_t)j * D4 + lane];
        float w1 = s_di[j];
        float w2 = ce[p] * co_s[j];
        float wz = ci_s[j];
        a1.x += w1 * v.x; a1.y += w1 * v.y; a1.z += w1 * v.z; a1.w += w1 * v.w;
        a2.x += w2 * v.x; a2.y += w2 * v.y; a2.z += w2 * v.z; a2.w += w2 * v.w;
        az.x += wz * v.x; az.y += wz * v.y; az.z += wz * v.z; az.w += wz * v.w;
        a3.x += u.x; a3.y += u.y; a3.z += u.z; a3.w += u.w;
    }
    float wd = d_o[wid] * co_s[wid];
    float4 vi = x4[(size_t)wid * D4 + lane];
    a2.x += wd * vi.x; a2.y += wd * vi.y; a2.z += wd * vi.z; a2.w += wd * vi.w;
    float c1 = 0.35f * s_do[wid];
    float c2 = 0.15f * ro_s[wid];
    float4 r;
    r.x = c1 * a1.x + c2 * (a3.x - a2.x);
    r.y = c1 * a1.y + c2 * (a3.y - a2.y);
    r.z = c1 * a1.z + c2 * (a3.z - a2.z);
    r.w = c1 * a1.w + c2 * (a3.w - a2.w);
    ((float4*)Y    )[(size_t)wid * D4 + lane] = r;
    ((float4*)z2out)[(size_t)wid * D4 + lane] = az;
}

// ---------------------------------------------------------------- pass C: Y[i] += 0.15*srow[i]*Sum_j z[j]
__global__ __launch_bounds__(256) void k_spmm_accum(const int* __restrict__ rp, const int* __restrict__ cols,
                                                    const float* __restrict__ zin, float* __restrict__ Y,
                                                    const float* __restrict__ srow) {
    int wid  = (blockIdx.x * blockDim.x + threadIdx.x) >> 6;
    int lane = threadIdx.x & 63;
    if (wid >= N_NODES) return;
    const float4* z4 = (const float4*)zin;
    float4 a = {0,0,0,0};
    int p0 = rp[wid], p1 = rp[wid + 1];
    int p = p0;
    for (; p + 4 <= p1; p += 4) {
        int j0 = cols[p], j1 = cols[p+1], j2 = cols[p+2], j3 = cols[p+3];
        float4 v0 = z4[(size_t)j0 * D4 + lane];
        float4 v1 = z4[(size_t)j1 * D4 + lane];
        float4 v2 = z4[(size_t)j2 * D4 + lane];
        float4 v3 = z4[(size_t)j3 * D4 + lane];
        a.x += v0.x + v1.x + v2.x + v3.x;
        a.y += v0.y + v1.y + v2.y + v3.y;
        a.z += v0.z + v1.z + v2.z + v3.z;
        a.w += v0.w + v1.w + v2.w + v3.w;
    }
    for (; p < p1; ++p) {
        int j = cols[p];
        float4 v = z4[(size_t)j * D4 + lane];
        a.x += v.x; a.y += v.y; a.z += v.z; a.w += v.w;
    }
    float s = 0.15f * srow[wid];
    float4* y4 = (float4*)Y;
    float4 cur = y4[(size_t)wid * D4 + lane];
    cur.x += s * a.x; cur.y += s * a.y; cur.z += s * a.z; cur.w += s * a.w;
    y4[(size_t)wid * D4 + lane] = cur;
}

// ---------------------------------------------------------------- GEMM partials: P = Y @ W^T  (one half per blockIdx.z)
// K-major LDS tiles, stride 68 floats (16B aligned rows, 4-bank row offset -> conflict-free b128 fragment reads)
__global__ __launch_bounds__(256) void k_sgemm2(const float* __restrict__ Ysrc, const float* __restrict__ Ydst,
                                                const float* __restrict__ Ws, const float* __restrict__ Wd,
                                                float* __restrict__ part0, float* __restrict__ part1) {
    const float* Y = blockIdx.z ? Ydst : Ysrc;
    const float* W = blockIdx.z ? Wd : Ws;
    float* P       = blockIdx.z ? part1 : part0;
    __shared__ float As[32][68];
    __shared__ float Bs[32][68];
    int tid = threadIdx.x;
    int tx = tid & 15, ty = tid >> 4;          // 16x16 threads, 4x4 outputs each
    int row0 = blockIdx.x * 64;
    int col0 = blockIdx.y * 64;
    int lr = tid >> 2;                          // 0..63: tile row loaded by this thread
    int lc = (tid & 3) * 8;                     // 8 consecutive k per thread
    float acc[4][4] = {};
    for (int k0 = 0; k0 < 256; k0 += 32) {
        float4 a0 = *(const float4*)&Y[(size_t)(row0 + lr) * 256 + k0 + lc];
        float4 a1 = *(const float4*)&Y[(size_t)(row0 + lr) * 256 + k0 + lc + 4];
        float4 b0 = *(const float4*)&W[(size_t)(col0 + lr) * 256 + k0 + lc];
        float4 b1 = *(const float4*)&W[(size_t)(col0 + lr) * 256 + k0 + lc + 4];
        __syncthreads();
        As[lc+0][lr] = a0.x; As[lc+1][lr] = a0.y; As[lc+2][lr] = a0.z; As[lc+3][lr] = a0.w;
        As[lc+4][lr] = a1.x; As[lc+5][lr] = a1.y; As[lc+6][lr] = a1.z; As[lc+7][lr] = a1.w;
        Bs[lc+0][lr] = b0.x; Bs[lc+1][lr] = b0.y; Bs[lc+2][lr] = b0.z; Bs[lc+3][lr] = b0.w;
        Bs[lc+4][lr] = b1.x; Bs[lc+5][lr] = b1.y; Bs[lc+6][lr] = b1.z; Bs[lc+7][lr] = b1.w;
        __syncthreads();
#pragma unroll
        for (int kk = 0; kk < 32; ++kk) {
            float4 av = *(const float4*)&As[kk][ty * 4];
            float4 bv = *(const float4*)&Bs[kk][tx * 4];
            acc[0][0] += av.x * bv.x; acc[0][1] += av.x * bv.y; acc[0][2] += av.x * bv.z; acc[0][3] += av.x * bv.w;
            acc[1][0] += av.y * bv.x; acc[1][1] += av.y * bv.y; acc[1][2] += av.y * bv.z; acc[1][3] += av.y * bv.w;
            acc[2][0] += av.z * bv.x; acc[2][1] += av.z * bv.y; acc[2][2] += av.z * bv.z; acc[2][3] += av.z * bv.w;
            acc[3][0] += av.w * bv.x; acc[3][1] += av.w * bv.y; acc[3][2] += av.w * bv.z; acc[3][3] += av.w * bv.w;
        }
    }
#pragma unroll
    for (int r = 0; r < 4; ++r) {
        int orow = row0 + ty * 4 + r;
        float4 v = { acc[r][0], acc[r][1], acc[r][2], acc[r][3] };
        *(float4*)&P[(size_t)orow * 256 + col0 + tx * 4] = v;
    }
}

// ---------------------------------------------------------------- combine: out = P0 + P1 + 0.5*(bs+bd)
__global__ __launch_bounds__(256) void k_combine(const float4* __restrict__ p0, const float4* __restrict__ p1,
                                                 const float4* __restrict__ bs4, const float4* __restrict__ bd4,
                                                 float4* __restrict__ out4) {
    int i = blockIdx.x * 256 + threadIdx.x;     // over 4096*64 float4
    float4 a = p0[i], b = p1[i];
    float4 s = bs4[i & 63], d = bd4[i & 63];
    float4 r;
    r.x = a.x + b.x + 0.5f * (s.x + d.x);
    r.y = a.y + b.y + 0.5f * (s.y + d.y);
    r.z = a.z + b.z + 0.5f * (s.z + d.z);
    r.w = a.w + b.w + 0.5f * (s.w + d.w);
    out4[i] = r;
}

// ---------------------------------------------------------------- launch
extern "C" void kernel_launch(void* const* d_in, const int* in_sizes, int n_in,
                              void* d_out, int out_size, void* d_ws, size_t ws_size,
                              hipStream_t stream) {
    const float* x  = (const float*)d_in[0];
    const int*   ei = (const int*)  d_in[1];
    const float* Ws = (const float*)d_in[2];
    const float* bs = (const float*)d_in[3];
    const float* Wd = (const float*)d_in[4];
    const float* bd = (const float*)d_in[5];
    float* out = (float*)d_out;

    char* ws = (char*)d_ws;
    size_t off = 0;
    auto alloc = [&](size_t bytes) -> void* {
        void* p = ws + off;
        off = (off + bytes + 255) & ~(size_t)255;
        return p;
    };
    u64*   Ab      = (u64*)  alloc((size_t)N_NODES * NWORDS * 8);   // 2 MB
    u64*   Atb     = (u64*)  alloc((size_t)N_NODES * NWORDS * 8);   // 2 MB (contiguous with Ab)
    float* csub_o  = (float*)alloc(N_NODES * 4);
    float* csub_i  = (float*)alloc(N_NODES * 4);                    // contiguous with csub_o
    float* d_o     = (float*)alloc(N_NODES * 4);
    float* d_i     = (float*)alloc(N_NODES * 4);
    int*   rp_o    = (int*)  alloc((N_NODES + 1) * 4);
    int*   rp_i    = (int*)  alloc((N_NODES + 1) * 4);
    int*   col_o   = (int*)  alloc((size_t)E_EDGES * 4);
    int*   col_i   = (int*)  alloc((size_t)E_EDGES * 4);
    float* ce_o    = (float*)alloc((size_t)E_EDGES * 4);
    float* ce_i    = (float*)alloc((size_t)E_EDGES * 4);
    float* rfull_o = (float*)alloc(N_NODES * 4);
    float* rsub_o  = (float*)alloc(N_NODES * 4);
    float* rfull_i = (float*)alloc(N_NODES * 4);
    float* rsub_i  = (float*)alloc(N_NODES * 4);
    float* s_do    = (float*)alloc(N_NODES * 4);
    float* s_di    = (float*)alloc(N_NODES * 4);
    float* ro_s    = (float*)alloc(N_NODES * 4);
    float* co_s    = (float*)alloc(N_NODES * 4);
    float* ri_s    = (float*)alloc(N_NODES * 4);
    float* ci_s    = (float*)alloc(N_NODES * 4);
    float* zbuf    = (float*)alloc((size_t)N_NODES * D_FEAT * 4);   // 4 MB
    float* z2buf   = (float*)alloc((size_t)N_NODES * D_FEAT * 4);   // 4 MB
    float* Ysrc    = (float*)alloc((size_t)N_NODES * D_FEAT * 4);   // 4 MB
    float* Ydst    = (float*)alloc((size_t)N_NODES * D_FEAT * 4);   // 4 MB
    float* part0   = (float*)alloc((size_t)N_NODES * D_FEAT * 4);   // 4 MB
    float* part1   = (float*)alloc((size_t)N_NODES * D_FEAT * 4);   // 4 MB

    // zero bitsets (Ab+Atb contiguous) and csub arrays (contiguous)
    hipMemsetAsync(Ab, 0, (size_t)N_NODES * NWORDS * 8 * 2, stream);
    hipMemsetAsync(csub_o, 0, (size_t)N_NODES * 4 * 2, stream);

    k_scatter<<<(E_EDGES + 255) / 256, 256, 0, stream>>>(ei, Ab, Atb);
    k_degrees<<<(N_NODES * 64) / 256, 256, 0, stream>>>(Ab, Atb, d_o, d_i);
    k_prefix2<<<1, 1024, 0, stream>>>(d_o, rp_o, d_i, rp_i);
    k_fill_csr2<<<(2 * N_NODES * 64) / 256, 256, 0, stream>>>(Ab, rp_o, col_o, Atb, rp_i, col_i);
    // SO_out: succ-bitset intersections (rfull uses d_in). SO_in: pred-bitsets (rfull uses d_out).
    k_so_edges2<<<(2 * N_NODES * 64) / 256, 256, 0, stream>>>(Ab,  rp_o, col_o, d_i, ce_o, rfull_o, rsub_o, csub_o,
                                                              Atb, rp_i, col_i, d_o, ce_i, rfull_i, rsub_i, csub_i);
    k_finalize<<<(N_NODES + 255) / 256, 256, 0, stream>>>(d_o, d_i, rfull_o, rsub_o, csub_o,
                                                          rfull_i, rsub_i, csub_i,
                                                          s_do, s_di, ro_s, co_s, ri_s, ci_s);
    // Pass A (csr_in): Ydst = 0.35*At_n@x - 0.15*mask-corr(SO_in);  z = At@(co_s*x)
    k_fused_pass<<<(N_NODES * 64) / 256, 256, 0, stream>>>(rp_i, col_i, ce_i, x, Ydst, zbuf,
                                                           s_di, s_do, ri_s, ci_s, co_s, d_i);
    // Pass B (csr_out, fused): Ysrc = 0.35*A_n@x + 0.15*ro_s*(A@z - corr);  z2 = A@(ci_s*x)
    k_pass_b<<<(N_NODES * 64) / 256, 256, 0, stream>>>(rp_o, col_o, ce_o, x, zbuf, Ysrc, z2buf,
                                                       s_do, s_di, ro_s, co_s, ci_s, d_o);
    // Pass C: Ydst += 0.15*ri_s*(At@z2)
    k_spmm_accum<<<(N_NODES * 64) / 256, 256, 0, stream>>>(rp_i, col_i, z2buf, Ydst, ri_s);
    // Final GEMM halves then combine with bias
    k_sgemm2<<<dim3(N_NODES / 64, D_FEAT / 64, 2), 256, 0, stream>>>(Ysrc, Ydst, Ws, Wd, part0, part1);
    k_combine<<<(N_NODES * D_FEAT / 4) / 256, 256, 0, stream>>>((const float4*)part0, (const float4*)part1,
                                                                (const float4*)bs, (const float4*)bd,
                                                                (float4*)out);
}

// Round 6
// 175.278 us; speedup vs baseline: 2.1048x; 1.0402x over previous
//
#include <hip/hip_runtime.h>
#include <cstdint>
#include <cstddef>

#define N_NODES 4096
#define NWORDS  64          // 4096 bits / 64
#define E_EDGES 131072
#define D_FEAT  256
#define D4      (D_FEAT/4)  // 64 float4 per row
#define ELL     128         // fixed slots per node (Poisson(32) -> P(deg>128) ~ 1e-40)

typedef unsigned long long u64;

// ---------------------------------------------------------------- scatter
__global__ __launch_bounds__(256) void k_scatter(const int* __restrict__ ei,
                                                 u64* __restrict__ Ab, u64* __restrict__ Atb) {
    int e = blockIdx.x * 256 + threadIdx.x;
    if (e >= E_EDGES) return;
    int r = ei[e];
    int c = ei[E_EDGES + e];
    atomicOr(&Ab [(size_t)r * NWORDS + (c >> 6)], 1ull << (c & 63));
    atomicOr(&Atb[(size_t)c * NWORDS + (r >> 6)], 1ull << (r & 63));
}

// ---------------------------------------------------------------- ELL fill + degrees, both directions (wave per node)
// Wave prefix-scan of per-lane popcounts; lane63 inclusive total == degree.
__global__ __launch_bounds__(256) void k_fill_deg(const u64* __restrict__ Ab,  int* __restrict__ col_o,
                                                  float* __restrict__ d_o, int* __restrict__ ideg_o,
                                                  const u64* __restrict__ Atb, int* __restrict__ col_i,
                                                  float* __restrict__ d_i, int* __restrict__ ideg_i) {
    int gw   = (blockIdx.x * blockDim.x + threadIdx.x) >> 6;
    int lane = threadIdx.x & 63;
    if (gw >= 2 * N_NODES) return;
    int half = gw >= N_NODES;
    int wid  = half ? gw - N_NODES : gw;
    const u64* bits = half ? Atb : Ab;
    int*       cols = half ? col_i : col_o;
    float*     dd   = half ? d_i   : d_o;
    int*       idg  = half ? ideg_i : ideg_o;
    u64 wv = bits[(size_t)wid * NWORDS + lane];
    int cnt = __popcll(wv);
    int inc = cnt;
    for (int off = 1; off < 64; off <<= 1) {
        int t = __shfl_up(inc, off);
        if (lane >= off) inc += t;
    }
    int pos = (wid << 7) + inc - cnt;   // ELL base + exclusive prefix
    while (wv) {
        int t = __builtin_ctzll(wv);
        cols[pos++] = lane * 64 + t;
        wv &= wv - 1;
    }
    if (lane == 63) { dd[wid] = (float)inc; idg[wid] = inc; }
}

// ---------------------------------------------------------------- per-edge common-neighbor counts, both directions (4 edges/wave)
// 16-lane groups: group g handles edges p0+g, p0+g+4, ...; lane s holds words 4s..4s+3.
__global__ __launch_bounds__(256) void k_so_edges2(const u64* __restrict__ Ab,  const int* __restrict__ ideg_o, const int* __restrict__ col_o,
                                                   const float* __restrict__ d_i_arr, float* __restrict__ ce_o, float* __restrict__ rfull_o,
                                                   float* __restrict__ rsub_o, float* __restrict__ csub_o,
                                                   const u64* __restrict__ Atb, const int* __restrict__ ideg_i, const int* __restrict__ col_i,
                                                   const float* __restrict__ d_o_arr, float* __restrict__ ce_i, float* __restrict__ rfull_i,
                                                   float* __restrict__ rsub_i, float* __restrict__ csub_i) {
    int gw   = (blockIdx.x * blockDim.x + threadIdx.x) >> 6;
    int lane = threadIdx.x & 63;
    if (gw >= 2 * N_NODES) return;
    int half = gw >= N_NODES;
    int wid  = half ? gw - N_NODES : gw;
    const u64*   bits  = half ? Atb     : Ab;
    const int*   idg   = half ? ideg_i  : ideg_o;
    const int*   cols  = half ? col_i   : col_o;
    const float* dcol  = half ? d_o_arr : d_i_arr;
    float*       ce    = half ? ce_i    : ce_o;
    float*       rfull = half ? rfull_i : rfull_o;
    float*       rsub  = half ? rsub_i  : rsub_o;
    float*       csub  = half ? csub_i  : csub_o;
    int g = lane >> 4, s = lane & 15;
    const u64* aw = &bits[(size_t)wid * NWORDS + s * 4];
    u64 a0 = aw[0], a1 = aw[1], a2 = aw[2], a3 = aw[3];
    int p0 = wid << 7, p1 = p0 + idg[wid];
    float rf = 0.f, rs = 0.f;
    for (int p = p0 + g; p < p1; p += 4) {
        int j = cols[p];
        const u64* bw = &bits[(size_t)j * NWORDS + s * 4];
        u64 b0 = bw[0], b1 = bw[1], b2 = bw[2], b3 = bw[3];
        int c = __popcll(a0 & b0) + __popcll(a1 & b1) + __popcll(a2 & b2) + __popcll(a3 & b3);
        c += __shfl_xor(c, 1);
        c += __shfl_xor(c, 2);
        c += __shfl_xor(c, 4);
        c += __shfl_xor(c, 8);
        if (s == 0) {
            float cf = (j == wid) ? 0.f : (float)c;   // self-loop handled by diag term
            ce[p] = cf;
            if (cf != 0.f) atomicAdd(&csub[j], cf);
            rs += cf;
            rf += dcol[j];
        }
    }
    rf += __shfl_xor(rf, 16); rf += __shfl_xor(rf, 32);
    rs += __shfl_xor(rs, 16); rs += __shfl_xor(rs, 32);
    if (lane == 0) { rfull[wid] = rf; rsub[wid] = rs; }
}

// ---------------------------------------------------------------- scales
__global__ __launch_bounds__(256) void k_finalize(const float* __restrict__ dout, const float* __restrict__ din,
                                                  const float* __restrict__ rfo, const float* __restrict__ rso, const float* __restrict__ cso,
                                                  const float* __restrict__ rfi, const float* __restrict__ rsi, const float* __restrict__ csi,
                                                  float* __restrict__ s_do, float* __restrict__ s_di,
                                                  float* __restrict__ ro_s, float* __restrict__ co_s,
                                                  float* __restrict__ ri_s, float* __restrict__ ci_s) {
    int i = blockIdx.x * blockDim.x + threadIdx.x;
    if (i >= N_NODES) return;
    float d_o = dout[i], d_i = din[i];
    s_do[i] = d_o > 0.f ? rsqrtf(d_o) : 0.f;
    s_di[i] = d_i > 0.f ? rsqrtf(d_i) : 0.f;
    float ro = rfo[i] - d_o - rso[i];   // masked SO_out row sum
    float co = rfo[i] - d_o - cso[i];   // masked SO_out col sum (full matrix symmetric)
    float ri = rfi[i] - d_i - rsi[i];   // masked SO_in row sum
    float ci = rfi[i] - d_i - csi[i];   // masked SO_in col sum
    ro_s[i] = ro > 0.f ? rsqrtf(ro) : 0.f;
    co_s[i] = co > 0.f ? rsqrtf(co) : 0.f;
    ri_s[i] = ri > 0.f ? rsqrtf(ri) : 0.f;
    ci_s[i] = ci > 0.f ? rsqrtf(ci) : 0.f;
}

// ---------------------------------------------------------------- pass A (csr_in): Ydst partial + z
// Ydst[i] = 0.35*s_di[i]*Sum_j s_do[j]*x[j] - 0.15*ri_s[i]*( Sum_j ce*ci_s[j]*x[j] + d_i[i]*ci_s[i]*x[i] )
// z[i]    = Sum_j co_s[j]*x[j]
__global__ __launch_bounds__(256) void k_fused_pass(const int* __restrict__ idg, const int* __restrict__ cols,
                                                    const float* __restrict__ ce, const float* __restrict__ x,
                                                    float* __restrict__ Y, float* __restrict__ zout,
                                                    const float* __restrict__ srow_fo, const float* __restrict__ scol_fo,
                                                    const float* __restrict__ srow_so, const float* __restrict__ scol_so,
                                                    const float* __restrict__ scol_z, const float* __restrict__ dself) {
    int wid  = (blockIdx.x * blockDim.x + threadIdx.x) >> 6;
    int lane = threadIdx.x & 63;
    if (wid >= N_NODES) return;
    const float4* x4 = (const float4*)x;
    float4 a1 = {0,0,0,0}, a2 = {0,0,0,0}, az = {0,0,0,0};
    int p0 = wid << 7, p1 = p0 + idg[wid];
    int p = p0;
    for (; p + 4 <= p1; p += 4) {
        int j0 = cols[p], j1 = cols[p+1], j2 = cols[p+2], j3 = cols[p+3];
        float4 v0 = x4[(size_t)j0 * D4 + lane];
        float4 v1 = x4[(size_t)j1 * D4 + lane];
        float4 v2 = x4[(size_t)j2 * D4 + lane];
        float4 v3 = x4[(size_t)j3 * D4 + lane];
        float f0 = scol_fo[j0], f1 = scol_fo[j1], f2 = scol_fo[j2], f3 = scol_fo[j3];
        float s0 = ce[p]   * scol_so[j0];
        float s1 = ce[p+1] * scol_so[j1];
        float s2 = ce[p+2] * scol_so[j2];
        float s3 = ce[p+3] * scol_so[j3];
        float z0 = scol_z[j0], z1 = scol_z[j1], z2 = scol_z[j2], z3 = scol_z[j3];
        a1.x += f0*v0.x + f1*v1.x + f2*v2.x + f3*v3.x;
        a1.y += f0*v0.y + f1*v1.y + f2*v2.y + f3*v3.y;
        a1.z += f0*v0.z + f1*v1.z + f2*v2.z + f3*v3.z;
        a1.w += f0*v0.w + f1*v1.w + f2*v2.w + f3*v3.w;
        a2.x += s0*v0.x + s1*v1.x + s2*v2.x + s3*v3.x;
        a2.y += s0*v0.y + s1*v1.y + s2*v2.y + s3*v3.y;
        a2.z += s0*v0.z + s1*v1.z + s2*v2.z + s3*v3.z;
        a2.w += s0*v0.w + s1*v1.w + s2*v2.w + s3*v3.w;
        az.x += z0*v0.x + z1*v1.x + z2*v2.x + z3*v3.x;
        az.y += z0*v0.y + z1*v1.y + z2*v2.y + z3*v3.y;
        az.z += z0*v0.z + z1*v1.z + z2*v2.z + z3*v3.z;
        az.w += z0*v0.w + z1*v1.w + z2*v2.w + z3*v3.w;
    }
    for (; p < p1; ++p) {
        int j = cols[p];
        float w1 = scol_fo[j];
        float w2 = ce[p] * scol_so[j];
        float wz = scol_z[j];
        float4 v = x4[(size_t)j * D4 + lane];
        a1.x += w1 * v.x; a1.y += w1 * v.y; a1.z += w1 * v.z; a1.w += w1 * v.w;
        a2.x += w2 * v.x; a2.y += w2 * v.y; a2.z += w2 * v.z; a2.w += w2 * v.w;
        az.x += wz * v.x; az.y += wz * v.y; az.z += wz * v.z; az.w += wz * v.w;
    }
    float wd = dself[wid] * scol_so[wid];
    float4 vi = x4[(size_t)wid * D4 + lane];
    a2.x += wd * vi.x; a2.y += wd * vi.y; a2.z += wd * vi.z; a2.w += wd * vi.w;
    float c1 = 0.35f * srow_fo[wid];
    float c2 = -0.15f * srow_so[wid];
    float4 r;
    r.x = c1 * a1.x + c2 * a2.x;
    r.y = c1 * a1.y + c2 * a2.y;
    r.z = c1 * a1.z + c2 * a2.z;
    r.w = c1 * a1.w + c2 * a2.w;
    ((float4*)Y   )[(size_t)wid * D4 + lane] = r;
    ((float4*)zout)[(size_t)wid * D4 + lane] = az;
}

// ---------------------------------------------------------------- pass B (csr_out, fused): full Ysrc + z2
// Ysrc[i] = 0.35*s_do[i]*Sum_j s_di[j]*x[j]
//         + 0.15*ro_s[i]*( Sum_j z[j]  -  Sum_j ce*co_s[j]*x[j] - d_o[i]*co_s[i]*x[i] )
// z2[i]   = Sum_j ci_s[j]*x[j]
__global__ __launch_bounds__(256) void k_pass_b(const int* __restrict__ idg, const int* __restrict__ cols,
                                                const float* __restrict__ ce, const float* __restrict__ x,
                                                const float* __restrict__ zin,
                                                float* __restrict__ Y, float* __restrict__ z2out,
                                                const float* __restrict__ s_do, const float* __restrict__ s_di,
                                                const float* __restrict__ ro_s, const float* __restrict__ co_s,
                                                const float* __restrict__ ci_s, const float* __restrict__ d_o) {
    int wid  = (blockIdx.x * blockDim.x + threadIdx.x) >> 6;
    int lane = threadIdx.x & 63;
    if (wid >= N_NODES) return;
    const float4* x4 = (const float4*)x;
    const float4* z4 = (const float4*)zin;
    float4 a1 = {0,0,0,0}, a2 = {0,0,0,0}, az = {0,0,0,0}, a3 = {0,0,0,0};
    int p0 = wid << 7, p1 = p0 + idg[wid];
    int p = p0;
    for (; p + 2 <= p1; p += 2) {
        int j0 = cols[p], j1 = cols[p+1];
        float4 v0 = x4[(size_t)j0 * D4 + lane];
        float4 v1 = x4[(size_t)j1 * D4 + lane];
        float4 u0 = z4[(size_t)j0 * D4 + lane];
        float4 u1 = z4[(size_t)j1 * D4 + lane];
        float f0 = s_di[j0], f1 = s_di[j1];
        float s0 = ce[p]   * co_s[j0];
        float s1 = ce[p+1] * co_s[j1];
        float w0 = ci_s[j0], w1 = ci_s[j1];
        a1.x += f0*v0.x + f1*v1.x;  a1.y += f0*v0.y + f1*v1.y;
        a1.z += f0*v0.z + f1*v1.z;  a1.w += f0*v0.w + f1*v1.w;
        a2.x += s0*v0.x + s1*v1.x;  a2.y += s0*v0.y + s1*v1.y;
        a2.z += s0*v0.z + s1*v1.z;  a2.w += s0*v0.w + s1*v1.w;
        az.x += w0*v0.x + w1*v1.x;  az.y += w0*v0.y + w1*v1.y;
        az.z += w0*v0.z + w1*v1.z;  az.w += w0*v0.w + w1*v1.w;
        a3.x += u0.x + u1.x;  a3.y += u0.y + u1.y;
        a3.z += u0.z + u1.z;  a3.w += u0.w + u1.w;
    }
    for (; p < p1; ++p) {
        int j = cols[p];
        float4 v = x4[(size_t)j * D4 + lane];
        float4 u = z4[(size_t)j * D4 + lane];
        float w1 = s_di[j];
        float w2 = ce[p] * co_s[j];
        float wz = ci_s[j];
        a1.x += w1 * v.x; a1.y += w1 * v.y; a1.z += w1 * v.z; a1.w += w1 * v.w;
        a2.x += w2 * v.x; a2.y += w2 * v.y; a2.z += w2 * v.z; a2.w += w2 * v.w;
        az.x += wz * v.x; az.y += wz * v.y; az.z += wz * v.z; az.w += wz * v.w;
        a3.x += u.x; a3.y += u.y; a3.z += u.z; a3.w += u.w;
    }
    float wd = d_o[wid] * co_s[wid];
    float4 vi = x4[(size_t)wid * D4 + lane];
    a2.x += wd * vi.x; a2.y += wd * vi.y; a2.z += wd * vi.z; a2.w += wd * vi.w;
    float c1 = 0.35f * s_do[wid];
    float c2 = 0.15f * ro_s[wid];
    float4 r;
    r.x = c1 * a1.x + c2 * (a3.x - a2.x);
    r.y = c1 * a1.y + c2 * (a3.y - a2.y);
    r.z = c1 * a1.z + c2 * (a3.z - a2.z);
    r.w = c1 * a1.w + c2 * (a3.w - a2.w);
    ((float4*)Y    )[(size_t)wid * D4 + lane] = r;
    ((float4*)z2out)[(size_t)wid * D4 + lane] = az;
}

// ---------------------------------------------------------------- pass C: Y[i] += 0.15*srow[i]*Sum_j z[j]
__global__ __launch_bounds__(256) void k_spmm_accum(const int* __restrict__ idg, const int* __restrict__ cols,
                                                    const float* __restrict__ zin, float* __restrict__ Y,
                                                    const float* __restrict__ srow) {
    int wid  = (blockIdx.x * blockDim.x + threadIdx.x) >> 6;
    int lane = threadIdx.x & 63;
    if (wid >= N_NODES) return;
    const float4* z4 = (const float4*)zin;
    float4 a = {0,0,0,0};
    int p0 = wid << 7, p1 = p0 + idg[wid];
    int p = p0;
    for (; p + 4 <= p1; p += 4) {
        int j0 = cols[p], j1 = cols[p+1], j2 = cols[p+2], j3 = cols[p+3];
        float4 v0 = z4[(size_t)j0 * D4 + lane];
        float4 v1 = z4[(size_t)j1 * D4 + lane];
        float4 v2 = z4[(size_t)j2 * D4 + lane];
        float4 v3 = z4[(size_t)j3 * D4 + lane];
        a.x += v0.x + v1.x + v2.x + v3.x;
        a.y += v0.y + v1.y + v2.y + v3.y;
        a.z += v0.z + v1.z + v2.z + v3.z;
        a.w += v0.w + v1.w + v2.w + v3.w;
    }
    for (; p < p1; ++p) {
        int j = cols[p];
        float4 v = z4[(size_t)j * D4 + lane];
        a.x += v.x; a.y += v.y; a.z += v.z; a.w += v.w;
    }
    float s = 0.15f * srow[wid];
    float4* y4 = (float4*)Y;
    float4 cur = y4[(size_t)wid * D4 + lane];
    cur.x += s * a.x; cur.y += s * a.y; cur.z += s * a.z; cur.w += s * a.w;
    y4[(size_t)wid * D4 + lane] = cur;
}

// ---------------------------------------------------------------- GEMM partials: P = Y @ W^T  (one half per blockIdx.z)
// K-major LDS tiles, stride 68 floats (16B aligned rows, 4-bank row offset -> conflict-free b128 fragment reads)
__global__ __launch_bounds__(256) void k_sgemm2(const float* __restrict__ Ysrc, const float* __restrict__ Ydst,
                                                const float* __restrict__ Ws, const float* __restrict__ Wd,
                                                float* __restrict__ part0, float* __restrict__ part1) {
    const float* Y = blockIdx.z ? Ydst : Ysrc;
    const float* W = blockIdx.z ? Wd : Ws;
    float* P       = blockIdx.z ? part1 : part0;
    __shared__ float As[32][68];
    __shared__ float Bs[32][68];
    int tid = threadIdx.x;
    int tx = tid & 15, ty = tid >> 4;          // 16x16 threads, 4x4 outputs each
    int row0 = blockIdx.x * 64;
    int col0 = blockIdx.y * 64;
    int lr = tid >> 2;                          // 0..63: tile row loaded by this thread
    int lc = (tid & 3) * 8;                     // 8 consecutive k per thread
    float acc[4][4] = {};
    for (int k0 = 0; k0 < 256; k0 += 32) {
        float4 a0 = *(const float4*)&Y[(size_t)(row0 + lr) * 256 + k0 + lc];
        float4 a1 = *(const float4*)&Y[(size_t)(row0 + lr) * 256 + k0 + lc + 4];
        float4 b0 = *(const float4*)&W[(size_t)(col0 + lr) * 256 + k0 + lc];
        float4 b1 = *(const float4*)&W[(size_t)(col0 + lr) * 256 + k0 + lc + 4];
        __syncthreads();
        As[lc+0][lr] = a0.x; As[lc+1][lr] = a0.y; As[lc+2][lr] = a0.z; As[lc+3][lr] = a0.w;
        As[lc+4][lr] = a1.x; As[lc+5][lr] = a1.y; As[lc+6][lr] = a1.z; As[lc+7][lr] = a1.w;
        Bs[lc+0][lr] = b0.x; Bs[lc+1][lr] = b0.y; Bs[lc+2][lr] = b0.z; Bs[lc+3][lr] = b0.w;
        Bs[lc+4][lr] = b1.x; Bs[lc+5][lr] = b1.y; Bs[lc+6][lr] = b1.z; Bs[lc+7][lr] = b1.w;
        __syncthreads();
#pragma unroll
        for (int kk = 0; kk < 32; ++kk) {
            float4 av = *(const float4*)&As[kk][ty * 4];
            float4 bv = *(const float4*)&Bs[kk][tx * 4];
            acc[0][0] += av.x * bv.x; acc[0][1] += av.x * bv.y; acc[0][2] += av.x * bv.z; acc[0][3] += av.x * bv.w;
            acc[1][0] += av.y * bv.x; acc[1][1] += av.y * bv.y; acc[1][2] += av.y * bv.z; acc[1][3] += av.y * bv.w;
            acc[2][0] += av.z * bv.x; acc[2][1] += av.z * bv.y; acc[2][2] += av.z * bv.z; acc[2][3] += av.z * bv.w;
            acc[3][0] += av.w * bv.x; acc[3][1] += av.w * bv.y; acc[3][2] += av.w * bv.z; acc[3][3] += av.w * bv.w;
        }
    }
#pragma unroll
    for (int r = 0; r < 4; ++r) {
        int orow = row0 + ty * 4 + r;
        float4 v = { acc[r][0], acc[r][1], acc[r][2], acc[r][3] };
        *(float4*)&P[(size_t)orow * 256 + col0 + tx * 4] = v;
    }
}

// ---------------------------------------------------------------- combine: out = P0 + P1 + 0.5*(bs+bd)
__global__ __launch_bounds__(256) void k_combine(const float4* __restrict__ p0, const float4* __restrict__ p1,
                                                 const float4* __restrict__ bs4, const float4* __restrict__ bd4,
                                                 float4* __restrict__ out4) {
    int i = blockIdx.x * 256 + threadIdx.x;     // over 4096*64 float4
    float4 a = p0[i], b = p1[i];
    float4 s = bs4[i & 63], d = bd4[i & 63];
    float4 r;
    r.x = a.x + b.x + 0.5f * (s.x + d.x);
    r.y = a.y + b.y + 0.5f * (s.y + d.y);
    r.z = a.z + b.z + 0.5f * (s.z + d.z);
    r.w = a.w + b.w + 0.5f * (s.w + d.w);
    out4[i] = r;
}

// ---------------------------------------------------------------- launch
extern "C" void kernel_launch(void* const* d_in, const int* in_sizes, int n_in,
                              void* d_out, int out_size, void* d_ws, size_t ws_size,
                              hipStream_t stream) {
    const float* x  = (const float*)d_in[0];
    const int*   ei = (const int*)  d_in[1];
    const float* Ws = (const float*)d_in[2];
    const float* bs = (const float*)d_in[3];
    const float* Wd = (const float*)d_in[4];
    const float* bd = (const float*)d_in[5];
    float* out = (float*)d_out;

    char* ws = (char*)d_ws;
    size_t off = 0;
    auto alloc = [&](size_t bytes) -> void* {
        void* p = ws + off;
        off = (off + bytes + 255) & ~(size_t)255;
        return p;
    };
    // Keep Ab|Atb|csub_o|csub_i contiguous: zeroed by ONE memset.
    u64*   Ab      = (u64*)  alloc((size_t)N_NODES * NWORDS * 8);   // 2 MB
    u64*   Atb     = (u64*)  alloc((size_t)N_NODES * NWORDS * 8);   // 2 MB
    float* csub_o  = (float*)alloc(N_NODES * 4);                    // 16 KB
    float* csub_i  = (float*)alloc(N_NODES * 4);                    // 16 KB
    float* d_o     = (float*)alloc(N_NODES * 4);
    float* d_i     = (float*)alloc(N_NODES * 4);
    int*   ideg_o  = (int*)  alloc(N_NODES * 4);
    int*   ideg_i  = (int*)  alloc(N_NODES * 4);
    int*   col_o   = (int*)  alloc((size_t)N_NODES * ELL * 4);      // 2 MB
    int*   col_i   = (int*)  alloc((size_t)N_NODES * ELL * 4);      // 2 MB
    float* ce_o    = (float*)alloc((size_t)N_NODES * ELL * 4);      // 2 MB
    float* ce_i    = (float*)alloc((size_t)N_NODES * ELL * 4);      // 2 MB
    float* rfull_o = (float*)alloc(N_NODES * 4);
    float* rsub_o  = (float*)alloc(N_NODES * 4);
    float* rfull_i = (float*)alloc(N_NODES * 4);
    float* rsub_i  = (float*)alloc(N_NODES * 4);
    float* s_do    = (float*)alloc(N_NODES * 4);
    float* s_di    = (float*)alloc(N_NODES * 4);
    float* ro_s    = (float*)alloc(N_NODES * 4);
    float* co_s    = (float*)alloc(N_NODES * 4);
    float* ri_s    = (float*)alloc(N_NODES * 4);
    float* ci_s    = (float*)alloc(N_NODES * 4);
    float* zbuf    = (float*)alloc((size_t)N_NODES * D_FEAT * 4);   // 4 MB
    float* z2buf   = (float*)alloc((size_t)N_NODES * D_FEAT * 4);   // 4 MB
    float* Ysrc    = (float*)alloc((size_t)N_NODES * D_FEAT * 4);   // 4 MB
    float* Ydst    = (float*)alloc((size_t)N_NODES * D_FEAT * 4);   // 4 MB
    float* part0   = (float*)alloc((size_t)N_NODES * D_FEAT * 4);   // 4 MB
    float* part1   = (float*)alloc((size_t)N_NODES * D_FEAT * 4);   // 4 MB

    // single zero-fill: Ab + Atb + csub_o + csub_i (contiguous, 256-aligned sizes)
    hipMemsetAsync(Ab, 0, (size_t)N_NODES * NWORDS * 8 * 2 + (size_t)N_NODES * 4 * 2, stream);

    k_scatter<<<(E_EDGES + 255) / 256, 256, 0, stream>>>(ei, Ab, Atb);
    k_fill_deg<<<(2 * N_NODES * 64) / 256, 256, 0, stream>>>(Ab, col_o, d_o, ideg_o,
                                                             Atb, col_i, d_i, ideg_i);
    // SO_out: succ-bitset intersections (rfull uses d_in). SO_in: pred-bitsets (rfull uses d_out).
    k_so_edges2<<<(2 * N_NODES * 64) / 256, 256, 0, stream>>>(Ab,  ideg_o, col_o, d_i, ce_o, rfull_o, rsub_o, csub_o,
                                                              Atb, ideg_i, col_i, d_o, ce_i, rfull_i, rsub_i, csub_i);
    k_finalize<<<(N_NODES + 255) / 256, 256, 0, stream>>>(d_o, d_i, rfull_o, rsub_o, csub_o,
                                                          rfull_i, rsub_i, csub_i,
                                                          s_do, s_di, ro_s, co_s, ri_s, ci_s);
    // Pass A (csr_in): Ydst = 0.35*At_n@x - 0.15*mask-corr(SO_in);  z = At@(co_s*x)
    k_fused_pass<<<(N_NODES * 64) / 256, 256, 0, stream>>>(ideg_i, col_i, ce_i, x, Ydst, zbuf,
                                                           s_di, s_do, ri_s, ci_s, co_s, d_i);
    // Pass B (csr_out, fused): Ysrc = 0.35*A_n@x + 0.15*ro_s*(A@z - corr);  z2 = A@(ci_s*x)
    k_pass_b<<<(N_NODES * 64) / 256, 256, 0, stream>>>(ideg_o, col_o, ce_o, x, zbuf, Ysrc, z2buf,
                                                       s_do, s_di, ro_s, co_s, ci_s, d_o);
    // Pass C: Ydst += 0.15*ri_s*(At@z2)
    k_spmm_accum<<<(N_NODES * 64) / 256, 256, 0, stream>>>(ideg_i, col_i, z2buf, Ydst, ri_s);
    // Final GEMM halves then combine with bias
    k_sgemm2<<<dim3(N_NODES / 64, D_FEAT / 64, 2), 256, 0, stream>>>(Ysrc, Ydst, Ws, Wd, part0, part1);
    k_combine<<<(N_NODES * D_FEAT / 4) / 256, 256, 0, stream>>>((const float4*)part0, (const float4*)part1,
                                                                (const float4*)bs, (const float4*)bd,
                                                                (float4*)out);
}

// Round 7
// 172.972 us; speedup vs baseline: 2.1329x; 1.0133x over previous
//
#include <hip/hip_runtime.h>
#include <cstdint>
#include <cstddef>

#define N_NODES 4096
#define NWORDS  64          // 4096 bits / 64
#define E_EDGES 131072
#define D_FEAT  256
#define D4      (D_FEAT/4)  // 64 float4 / ushort4 groups per row (4 feats per lane)
#define ELL     128         // fixed slots per node (Poisson(32) -> P(deg>128) ~ 1e-40)

typedef unsigned long long u64;

__device__ inline float bf2f(unsigned short u) {
    return __uint_as_float(((unsigned int)u) << 16);
}
__device__ inline unsigned short f2bf(float f) {   // round-to-nearest-even
    unsigned int u = __float_as_uint(f);
    return (unsigned short)((u + 0x7fffu + ((u >> 16) & 1u)) >> 16);
}

// ---------------------------------------------------------------- scatter + x->bf16 convert (disjoint block ranges)
__global__ __launch_bounds__(256) void k_scatter_cvt(const int* __restrict__ ei,
                                                     u64* __restrict__ Ab, u64* __restrict__ Atb,
                                                     const float* __restrict__ x, unsigned short* __restrict__ xb) {
    int b = blockIdx.x;
    if (b < E_EDGES / 256) {
        int e = b * 256 + threadIdx.x;
        int r = ei[e];
        int c = ei[E_EDGES + e];
        atomicOr(&Ab [(size_t)r * NWORDS + (c >> 6)], 1ull << (c & 63));
        atomicOr(&Atb[(size_t)c * NWORDS + (r >> 6)], 1ull << (r & 63));
    } else {
        int i = (b - E_EDGES / 256) * 256 + threadIdx.x;   // over N*D/4 groups
        float4 v = ((const float4*)x)[i];
        ushort4 q = { f2bf(v.x), f2bf(v.y), f2bf(v.z), f2bf(v.w) };
        ((ushort4*)xb)[i] = q;
    }
}

// ---------------------------------------------------------------- ELL fill + degrees, both directions (wave per node)
__global__ __launch_bounds__(256) void k_fill_deg(const u64* __restrict__ Ab,  int* __restrict__ col_o,
                                                  float* __restrict__ d_o, int* __restrict__ ideg_o,
                                                  const u64* __restrict__ Atb, int* __restrict__ col_i,
                                                  float* __restrict__ d_i, int* __restrict__ ideg_i) {
    int gw   = (blockIdx.x * blockDim.x + threadIdx.x) >> 6;
    int lane = threadIdx.x & 63;
    if (gw >= 2 * N_NODES) return;
    int half = gw >= N_NODES;
    int wid  = half ? gw - N_NODES : gw;
    const u64* bits = half ? Atb : Ab;
    int*       cols = half ? col_i : col_o;
    float*     dd   = half ? d_i   : d_o;
    int*       idg  = half ? ideg_i : ideg_o;
    u64 wv = bits[(size_t)wid * NWORDS + lane];
    int cnt = __popcll(wv);
    int inc = cnt;
    for (int off = 1; off < 64; off <<= 1) {
        int t = __shfl_up(inc, off);
        if (lane >= off) inc += t;
    }
    int pos = (wid << 7) + inc - cnt;   // ELL base + exclusive prefix
    while (wv) {
        int t = __builtin_ctzll(wv);
        cols[pos++] = lane * 64 + t;
        wv &= wv - 1;
    }
    if (lane == 63) { dd[wid] = (float)inc; idg[wid] = inc; }
}

// ---------------------------------------------------------------- per-edge common-neighbor counts, both directions (4 edges/wave)
__global__ __launch_bounds__(256) void k_so_edges2(const u64* __restrict__ Ab,  const int* __restrict__ ideg_o, const int* __restrict__ col_o,
                                                   const float* __restrict__ d_i_arr, float* __restrict__ ce_o, float* __restrict__ rfull_o,
                                                   float* __restrict__ rsub_o, float* __restrict__ csub_o,
                                                   const u64* __restrict__ Atb, const int* __restrict__ ideg_i, const int* __restrict__ col_i,
                                                   const float* __restrict__ d_o_arr, float* __restrict__ ce_i, float* __restrict__ rfull_i,
                                                   float* __restrict__ rsub_i, float* __restrict__ csub_i) {
    int gw   = (blockIdx.x * blockDim.x + threadIdx.x) >> 6;
    int lane = threadIdx.x & 63;
    if (gw >= 2 * N_NODES) return;
    int half = gw >= N_NODES;
    int wid  = half ? gw - N_NODES : gw;
    const u64*   bits  = half ? Atb     : Ab;
    const int*   idg   = half ? ideg_i  : ideg_o;
    const int*   cols  = half ? col_i   : col_o;
    const float* dcol  = half ? d_o_arr : d_i_arr;
    float*       ce    = half ? ce_i    : ce_o;
    float*       rfull = half ? rfull_i : rfull_o;
    float*       rsub  = half ? rsub_i  : rsub_o;
    float*       csub  = half ? csub_i  : csub_o;
    int g = lane >> 4, s = lane & 15;
    const u64* aw = &bits[(size_t)wid * NWORDS + s * 4];
    u64 a0 = aw[0], a1 = aw[1], a2 = aw[2], a3 = aw[3];
    int p0 = wid << 7, p1 = p0 + idg[wid];
    float rf = 0.f, rs = 0.f;
    for (int p = p0 + g; p < p1; p += 4) {
        int j = cols[p];
        const u64* bw = &bits[(size_t)j * NWORDS + s * 4];
        u64 b0 = bw[0], b1 = bw[1], b2 = bw[2], b3 = bw[3];
        int c = __popcll(a0 & b0) + __popcll(a1 & b1) + __popcll(a2 & b2) + __popcll(a3 & b3);
        c += __shfl_xor(c, 1);
        c += __shfl_xor(c, 2);
        c += __shfl_xor(c, 4);
        c += __shfl_xor(c, 8);
        if (s == 0) {
            float cf = (j == wid) ? 0.f : (float)c;   // self-loop handled by diag term
            ce[p] = cf;
            if (cf != 0.f) atomicAdd(&csub[j], cf);
            rs += cf;
            rf += dcol[j];
        }
    }
    rf += __shfl_xor(rf, 16); rf += __shfl_xor(rf, 32);
    rs += __shfl_xor(rs, 16); rs += __shfl_xor(rs, 32);
    if (lane == 0) { rfull[wid] = rf; rsub[wid] = rs; }
}

// ---------------------------------------------------------------- scales
__global__ __launch_bounds__(256) void k_finalize(const float* __restrict__ dout, const float* __restrict__ din,
                                                  const float* __restrict__ rfo, const float* __restrict__ rso, const float* __restrict__ cso,
                                                  const float* __restrict__ rfi, const float* __restrict__ rsi, const float* __restrict__ csi,
                                                  float* __restrict__ s_do, float* __restrict__ s_di,
                                                  float* __restrict__ ro_s, float* __restrict__ co_s,
                                                  float* __restrict__ ri_s, float* __restrict__ ci_s) {
    int i = blockIdx.x * blockDim.x + threadIdx.x;
    if (i >= N_NODES) return;
    float d_o = dout[i], d_i = din[i];
    s_do[i] = d_o > 0.f ? rsqrtf(d_o) : 0.f;
    s_di[i] = d_i > 0.f ? rsqrtf(d_i) : 0.f;
    float ro = rfo[i] - d_o - rso[i];   // masked SO_out row sum
    float co = rfo[i] - d_o - cso[i];   // masked SO_out col sum
    float ri = rfi[i] - d_i - rsi[i];   // masked SO_in row sum
    float ci = rfi[i] - d_i - csi[i];   // masked SO_in col sum
    ro_s[i] = ro > 0.f ? rsqrtf(ro) : 0.f;
    co_s[i] = co > 0.f ? rsqrtf(co) : 0.f;
    ri_s[i] = ri > 0.f ? rsqrtf(ri) : 0.f;
    ci_s[i] = ci > 0.f ? rsqrtf(ci) : 0.f;
}

// ---------------------------------------------------------------- pass A (csr_in): Ydst partial + z (bf16 out)
// Ydst[i] = 0.35*s_di[i]*Sum_j s_do[j]*x[j] - 0.15*ri_s[i]*( Sum_j ce*ci_s[j]*x[j] + d_i[i]*ci_s[i]*x[i] )
// z[i]    = Sum_j co_s[j]*x[j]      (stored bf16)
__global__ __launch_bounds__(256) void k_fused_pass(const int* __restrict__ idg, const int* __restrict__ cols,
                                                    const float* __restrict__ ce, const unsigned short* __restrict__ xb,
                                                    float* __restrict__ Y, unsigned short* __restrict__ zout,
                                                    const float* __restrict__ srow_fo, const float* __restrict__ scol_fo,
                                                    const float* __restrict__ srow_so, const float* __restrict__ scol_so,
                                                    const float* __restrict__ scol_z, const float* __restrict__ dself) {
    int wid  = (blockIdx.x * blockDim.x + threadIdx.x) >> 6;
    int lane = threadIdx.x & 63;
    if (wid >= N_NODES) return;
    const ushort4* x4 = (const ushort4*)xb;
    float4 a1 = {0,0,0,0}, a2 = {0,0,0,0}, az = {0,0,0,0};
    int p0 = wid << 7, p1 = p0 + idg[wid];
    int p = p0;
    for (; p + 4 <= p1; p += 4) {
        int j0 = cols[p], j1 = cols[p+1], j2 = cols[p+2], j3 = cols[p+3];
        ushort4 q0 = x4[(size_t)j0 * D4 + lane];
        ushort4 q1 = x4[(size_t)j1 * D4 + lane];
        ushort4 q2 = x4[(size_t)j2 * D4 + lane];
        ushort4 q3 = x4[(size_t)j3 * D4 + lane];
        float f0 = scol_fo[j0], f1 = scol_fo[j1], f2 = scol_fo[j2], f3 = scol_fo[j3];
        float s0 = ce[p]   * scol_so[j0];
        float s1 = ce[p+1] * scol_so[j1];
        float s2 = ce[p+2] * scol_so[j2];
        float s3 = ce[p+3] * scol_so[j3];
        float z0 = scol_z[j0], z1 = scol_z[j1], z2 = scol_z[j2], z3 = scol_z[j3];
        float v0x = bf2f(q0.x), v0y = bf2f(q0.y), v0z = bf2f(q0.z), v0w = bf2f(q0.w);
        float v1x = bf2f(q1.x), v1y = bf2f(q1.y), v1z = bf2f(q1.z), v1w = bf2f(q1.w);
        float v2x = bf2f(q2.x), v2y = bf2f(q2.y), v2z = bf2f(q2.z), v2w = bf2f(q2.w);
        float v3x = bf2f(q3.x), v3y = bf2f(q3.y), v3z = bf2f(q3.z), v3w = bf2f(q3.w);
        a1.x += f0*v0x + f1*v1x + f2*v2x + f3*v3x;
        a1.y += f0*v0y + f1*v1y + f2*v2y + f3*v3y;
        a1.z += f0*v0z + f1*v1z + f2*v2z + f3*v3z;
        a1.w += f0*v0w + f1*v1w + f2*v2w + f3*v3w;
        a2.x += s0*v0x + s1*v1x + s2*v2x + s3*v3x;
        a2.y += s0*v0y + s1*v1y + s2*v2y + s3*v3y;
        a2.z += s0*v0z + s1*v1z + s2*v2z + s3*v3z;
        a2.w += s0*v0w + s1*v1w + s2*v2w + s3*v3w;
        az.x += z0*v0x + z1*v1x + z2*v2x + z3*v3x;
        az.y += z0*v0y + z1*v1y + z2*v2y + z3*v3y;
        az.z += z0*v0z + z1*v1z + z2*v2z + z3*v3z;
        az.w += z0*v0w + z1*v1w + z2*v2w + z3*v3w;
    }
    for (; p < p1; ++p) {
        int j = cols[p];
        float w1 = scol_fo[j];
        float w2 = ce[p] * scol_so[j];
        float wz = scol_z[j];
        ushort4 q = x4[(size_t)j * D4 + lane];
        float vx = bf2f(q.x), vy = bf2f(q.y), vz = bf2f(q.z), vw = bf2f(q.w);
        a1.x += w1 * vx; a1.y += w1 * vy; a1.z += w1 * vz; a1.w += w1 * vw;
        a2.x += w2 * vx; a2.y += w2 * vy; a2.z += w2 * vz; a2.w += w2 * vw;
        az.x += wz * vx; az.y += wz * vy; az.z += wz * vz; az.w += wz * vw;
    }
    float wd = dself[wid] * scol_so[wid];
    ushort4 qi = x4[(size_t)wid * D4 + lane];
    a2.x += wd * bf2f(qi.x); a2.y += wd * bf2f(qi.y); a2.z += wd * bf2f(qi.z); a2.w += wd * bf2f(qi.w);
    float c1 = 0.35f * srow_fo[wid];
    float c2 = -0.15f * srow_so[wid];
    float4 r;
    r.x = c1 * a1.x + c2 * a2.x;
    r.y = c1 * a1.y + c2 * a2.y;
    r.z = c1 * a1.z + c2 * a2.z;
    r.w = c1 * a1.w + c2 * a2.w;
    ((float4*)Y)[(size_t)wid * D4 + lane] = r;
    ushort4 zq = { f2bf(az.x), f2bf(az.y), f2bf(az.z), f2bf(az.w) };
    ((ushort4*)zout)[(size_t)wid * D4 + lane] = zq;
}

// ---------------------------------------------------------------- pass B (csr_out, fused): full Ysrc + z2 (bf16 in/out)
// Ysrc[i] = 0.35*s_do[i]*Sum_j s_di[j]*x[j]
//         + 0.15*ro_s[i]*( Sum_j z[j] - Sum_j ce*co_s[j]*x[j] - d_o[i]*co_s[i]*x[i] )
// z2[i]   = Sum_j ci_s[j]*x[j]      (stored bf16)
__global__ __launch_bounds__(256) void k_pass_b(const int* __restrict__ idg, const int* __restrict__ cols,
                                                const float* __restrict__ ce, const unsigned short* __restrict__ xb,
                                                const unsigned short* __restrict__ zin,
                                                float* __restrict__ Y, unsigned short* __restrict__ z2out,
                                                const float* __restrict__ s_do, const float* __restrict__ s_di,
                                                const float* __restrict__ ro_s, const float* __restrict__ co_s,
                                                const float* __restrict__ ci_s, const float* __restrict__ d_o) {
    int wid  = (blockIdx.x * blockDim.x + threadIdx.x) >> 6;
    int lane = threadIdx.x & 63;
    if (wid >= N_NODES) return;
    const ushort4* x4 = (const ushort4*)xb;
    const ushort4* z4 = (const ushort4*)zin;
    float4 a1 = {0,0,0,0}, a2 = {0,0,0,0}, az = {0,0,0,0}, a3 = {0,0,0,0};
    int p0 = wid << 7, p1 = p0 + idg[wid];
    int p = p0;
    for (; p + 2 <= p1; p += 2) {
        int j0 = cols[p], j1 = cols[p+1];
        ushort4 q0 = x4[(size_t)j0 * D4 + lane];
        ushort4 q1 = x4[(size_t)j1 * D4 + lane];
        ushort4 u0 = z4[(size_t)j0 * D4 + lane];
        ushort4 u1 = z4[(size_t)j1 * D4 + lane];
        float f0 = s_di[j0], f1 = s_di[j1];
        float s0 = ce[p]   * co_s[j0];
        float s1 = ce[p+1] * co_s[j1];
        float w0 = ci_s[j0], w1 = ci_s[j1];
        float v0x = bf2f(q0.x), v0y = bf2f(q0.y), v0z = bf2f(q0.z), v0w = bf2f(q0.w);
        float v1x = bf2f(q1.x), v1y = bf2f(q1.y), v1z = bf2f(q1.z), v1w = bf2f(q1.w);
        a1.x += f0*v0x + f1*v1x;  a1.y += f0*v0y + f1*v1y;
        a1.z += f0*v0z + f1*v1z;  a1.w += f0*v0w + f1*v1w;
        a2.x += s0*v0x + s1*v1x;  a2.y += s0*v0y + s1*v1y;
        a2.z += s0*v0z + s1*v1z;  a2.w += s0*v0w + s1*v1w;
        az.x += w0*v0x + w1*v1x;  az.y += w0*v0y + w1*v1y;
        az.z += w0*v0z + w1*v1z;  az.w += w0*v0w + w1*v1w;
        a3.x += bf2f(u0.x) + bf2f(u1.x);  a3.y += bf2f(u0.y) + bf2f(u1.y);
        a3.z += bf2f(u0.z) + bf2f(u1.z);  a3.w += bf2f(u0.w) + bf2f(u1.w);
    }
    for (; p < p1; ++p) {
        int j = cols[p];
        ushort4 q = x4[(size_t)j * D4 + lane];
        ushort4 u = z4[(size_t)j * D4 + lane];
        float w1 = s_di[j];
        float w2 = ce[p] * co_s[j];
        float wz = ci_s[j];
        float vx = bf2f(q.x), vy = bf2f(q.y), vz = bf2f(q.z), vw = bf2f(q.w);
        a1.x += w1 * vx; a1.y += w1 * vy; a1.z += w1 * vz; a1.w += w1 * vw;
        a2.x += w2 * vx; a2.y += w2 * vy; a2.z += w2 * vz; a2.w += w2 * vw;
        az.x += wz * vx; az.y += wz * vy; az.z += wz * vz; az.w += wz * vw;
        a3.x += bf2f(u.x); a3.y += bf2f(u.y); a3.z += bf2f(u.z); a3.w += bf2f(u.w);
    }
    float wd = d_o[wid] * co_s[wid];
    ushort4 qi = x4[(size_t)wid * D4 + lane];
    a2.x += wd * bf2f(qi.x); a2.y += wd * bf2f(qi.y); a2.z += wd * bf2f(qi.z); a2.w += wd * bf2f(qi.w);
    float c1 = 0.35f * s_do[wid];
    float c2 = 0.15f * ro_s[wid];
    float4 r;
    r.x = c1 * a1.x + c2 * (a3.x - a2.x);
    r.y = c1 * a1.y + c2 * (a3.y - a2.y);
    r.z = c1 * a1.z + c2 * (a3.z - a2.z);
    r.w = c1 * a1.w + c2 * (a3.w - a2.w);
    ((float4*)Y)[(size_t)wid * D4 + lane] = r;
    ushort4 zq = { f2bf(az.x), f2bf(az.y), f2bf(az.z), f2bf(az.w) };
    ((ushort4*)z2out)[(size_t)wid * D4 + lane] = zq;
}

// ---------------------------------------------------------------- pass C: Y[i] += 0.15*srow[i]*Sum_j z2[j]  (bf16 gather)
__global__ __launch_bounds__(256) void k_spmm_accum(const int* __restrict__ idg, const int* __restrict__ cols,
                                                    const unsigned short* __restrict__ zin, float* __restrict__ Y,
                                                    const float* __restrict__ srow) {
    int wid  = (blockIdx.x * blockDim.x + threadIdx.x) >> 6;
    int lane = threadIdx.x & 63;
    if (wid >= N_NODES) return;
    const ushort4* z4 = (const ushort4*)zin;
    float4 a = {0,0,0,0};
    int p0 = wid << 7, p1 = p0 + idg[wid];
    int p = p0;
    for (; p + 4 <= p1; p += 4) {
        int j0 = cols[p], j1 = cols[p+1], j2 = cols[p+2], j3 = cols[p+3];
        ushort4 v0 = z4[(size_t)j0 * D4 + lane];
        ushort4 v1 = z4[(size_t)j1 * D4 + lane];
        ushort4 v2 = z4[(size_t)j2 * D4 + lane];
        ushort4 v3 = z4[(size_t)j3 * D4 + lane];
        a.x += bf2f(v0.x) + bf2f(v1.x) + bf2f(v2.x) + bf2f(v3.x);
        a.y += bf2f(v0.y) + bf2f(v1.y) + bf2f(v2.y) + bf2f(v3.y);
        a.z += bf2f(v0.z) + bf2f(v1.z) + bf2f(v2.z) + bf2f(v3.z);
        a.w += bf2f(v0.w) + bf2f(v1.w) + bf2f(v2.w) + bf2f(v3.w);
    }
    for (; p < p1; ++p) {
        int j = cols[p];
        ushort4 v = z4[(size_t)j * D4 + lane];
        a.x += bf2f(v.x); a.y += bf2f(v.y); a.z += bf2f(v.z); a.w += bf2f(v.w);
    }
    float s = 0.15f * srow[wid];
    float4* y4 = (float4*)Y;
    float4 cur = y4[(size_t)wid * D4 + lane];
    cur.x += s * a.x; cur.y += s * a.y; cur.z += s * a.z; cur.w += s * a.w;
    y4[(size_t)wid * D4 + lane] = cur;
}

// ---------------------------------------------------------------- GEMM partials: P = Y @ W^T  (one half per blockIdx.z)
__global__ __launch_bounds__(256) void k_sgemm2(const float* __restrict__ Ysrc, const float* __restrict__ Ydst,
                                                const float* __restrict__ Ws, const float* __restrict__ Wd,
                                                float* __restrict__ part0, float* __restrict__ part1) {
    const float* Y = blockIdx.z ? Ydst : Ysrc;
    const float* W = blockIdx.z ? Wd : Ws;
    float* P       = blockIdx.z ? part1 : part0;
    __shared__ float As[32][68];
    __shared__ float Bs[32][68];
    int tid = threadIdx.x;
    int tx = tid & 15, ty = tid >> 4;          // 16x16 threads, 4x4 outputs each
    int row0 = blockIdx.x * 64;
    int col0 = blockIdx.y * 64;
    int lr = tid >> 2;
    int lc = (tid & 3) * 8;
    float acc[4][4] = {};
    for (int k0 = 0; k0 < 256; k0 += 32) {
        float4 a0 = *(const float4*)&Y[(size_t)(row0 + lr) * 256 + k0 + lc];
        float4 a1 = *(const float4*)&Y[(size_t)(row0 + lr) * 256 + k0 + lc + 4];
        float4 b0 = *(const float4*)&W[(size_t)(col0 + lr) * 256 + k0 + lc];
        float4 b1 = *(const float4*)&W[(size_t)(col0 + lr) * 256 + k0 + lc + 4];
        __syncthreads();
        As[lc+0][lr] = a0.x; As[lc+1][lr] = a0.y; As[lc+2][lr] = a0.z; As[lc+3][lr] = a0.w;
        As[lc+4][lr] = a1.x; As[lc+5][lr] = a1.y; As[lc+6][lr] = a1.z; As[lc+7][lr] = a1.w;
        Bs[lc+0][lr] = b0.x; Bs[lc+1][lr] = b0.y; Bs[lc+2][lr] = b0.z; Bs[lc+3][lr] = b0.w;
        Bs[lc+4][lr] = b1.x; Bs[lc+5][lr] = b1.y; Bs[lc+6][lr] = b1.z; Bs[lc+7][lr] = b1.w;
        __syncthreads();
#pragma unroll
        for (int kk = 0; kk < 32; ++kk) {
            float4 av = *(const float4*)&As[kk][ty * 4];
            float4 bv = *(const float4*)&Bs[kk][tx * 4];
            acc[0][0] += av.x * bv.x; acc[0][1] += av.x * bv.y; acc[0][2] += av.x * bv.z; acc[0][3] += av.x * bv.w;
            acc[1][0] += av.y * bv.x; acc[1][1] += av.y * bv.y; acc[1][2] += av.y * bv.z; acc[1][3] += av.y * bv.w;
            acc[2][0] += av.z * bv.x; acc[2][1] += av.z * bv.y; acc[2][2] += av.z * bv.z; acc[2][3] += av.z * bv.w;
            acc[3][0] += av.w * bv.x; acc[3][1] += av.w * bv.y; acc[3][2] += av.w * bv.z; acc[3][3] += av.w * bv.w;
        }
    }
#pragma unroll
    for (int r = 0; r < 4; ++r) {
        int orow = row0 + ty * 4 + r;
        float4 v = { acc[r][0], acc[r][1], acc[r][2], acc[r][3] };
        *(float4*)&P[(size_t)orow * 256 + col0 + tx * 4] = v;
    }
}

// ---------------------------------------------------------------- combine: out = P0 + P1 + 0.5*(bs+bd)
__global__ __launch_bounds__(256) void k_combine(const float4* __restrict__ p0, const float4* __restrict__ p1,
                                                 const float4* __restrict__ bs4, const float4* __restrict__ bd4,
                                                 float4* __restrict__ out4) {
    int i = blockIdx.x * 256 + threadIdx.x;
    float4 a = p0[i], b = p1[i];
    float4 s = bs4[i & 63], d = bd4[i & 63];
    float4 r;
    r.x = a.x + b.x + 0.5f * (s.x + d.x);
    r.y = a.y + b.y + 0.5f * (s.y + d.y);
    r.z = a.z + b.z + 0.5f * (s.z + d.z);
    r.w = a.w + b.w + 0.5f * (s.w + d.w);
    out4[i] = r;
}

// ---------------------------------------------------------------- launch
extern "C" void kernel_launch(void* const* d_in, const int* in_sizes, int n_in,
                              void* d_out, int out_size, void* d_ws, size_t ws_size,
                              hipStream_t stream) {
    const float* x  = (const float*)d_in[0];
    const int*   ei = (const int*)  d_in[1];
    const float* Ws = (const float*)d_in[2];
    const float* bs = (const float*)d_in[3];
    const float* Wd = (const float*)d_in[4];
    const float* bd = (const float*)d_in[5];
    float* out = (float*)d_out;

    char* ws = (char*)d_ws;
    size_t off = 0;
    auto alloc = [&](size_t bytes) -> void* {
        void* p = ws + off;
        off = (off + bytes + 255) & ~(size_t)255;
        return p;
    };
    // Keep Ab|Atb|csub_o|csub_i contiguous: zeroed by ONE memset.
    u64*   Ab      = (u64*)  alloc((size_t)N_NODES * NWORDS * 8);   // 2 MB
    u64*   Atb     = (u64*)  alloc((size_t)N_NODES * NWORDS * 8);   // 2 MB
    float* csub_o  = (float*)alloc(N_NODES * 4);
    float* csub_i  = (float*)alloc(N_NODES * 4);
    unsigned short* xb = (unsigned short*)alloc((size_t)N_NODES * D_FEAT * 2);   // 2 MB bf16
    float* d_o     = (float*)alloc(N_NODES * 4);
    float* d_i     = (float*)alloc(N_NODES * 4);
    int*   ideg_o  = (int*)  alloc(N_NODES * 4);
    int*   ideg_i  = (int*)  alloc(N_NODES * 4);
    int*   col_o   = (int*)  alloc((size_t)N_NODES * ELL * 4);      // 2 MB
    int*   col_i   = (int*)  alloc((size_t)N_NODES * ELL * 4);      // 2 MB
    float* ce_o    = (float*)alloc((size_t)N_NODES * ELL * 4);      // 2 MB
    float* ce_i    = (float*)alloc((size_t)N_NODES * ELL * 4);      // 2 MB
    float* rfull_o = (float*)alloc(N_NODES * 4);
    float* rsub_o  = (float*)alloc(N_NODES * 4);
    float* rfull_i = (float*)alloc(N_NODES * 4);
    float* rsub_i  = (float*)alloc(N_NODES * 4);
    float* s_do    = (float*)alloc(N_NODES * 4);
    float* s_di    = (float*)alloc(N_NODES * 4);
    float* ro_s    = (float*)alloc(N_NODES * 4);
    float* co_s    = (float*)alloc(N_NODES * 4);
    float* ri_s    = (float*)alloc(N_NODES * 4);
    float* ci_s    = (float*)alloc(N_NODES * 4);
    unsigned short* zbuf  = (unsigned short*)alloc((size_t)N_NODES * D_FEAT * 2);  // 2 MB bf16
    unsigned short* z2buf = (unsigned short*)alloc((size_t)N_NODES * D_FEAT * 2);  // 2 MB bf16
    float* Ysrc    = (float*)alloc((size_t)N_NODES * D_FEAT * 4);   // 4 MB
    float* Ydst    = (float*)alloc((size_t)N_NODES * D_FEAT * 4);   // 4 MB
    float* part0   = (float*)alloc((size_t)N_NODES * D_FEAT * 4);   // 4 MB
    float* part1   = (float*)alloc((size_t)N_NODES * D_FEAT * 4);   // 4 MB

    // single zero-fill: Ab + Atb + csub_o + csub_i (contiguous)
    hipMemsetAsync(Ab, 0, (size_t)N_NODES * NWORDS * 8 * 2 + (size_t)N_NODES * 4 * 2, stream);

    // scatter (512 blocks) + x->bf16 convert (1024 blocks) in one dispatch
    k_scatter_cvt<<<E_EDGES / 256 + (N_NODES * D_FEAT / 4) / 256, 256, 0, stream>>>(ei, Ab, Atb, x, xb);
    k_fill_deg<<<(2 * N_NODES * 64) / 256, 256, 0, stream>>>(Ab, col_o, d_o, ideg_o,
                                                             Atb, col_i, d_i, ideg_i);
    k_so_edges2<<<(2 * N_NODES * 64) / 256, 256, 0, stream>>>(Ab,  ideg_o, col_o, d_i, ce_o, rfull_o, rsub_o, csub_o,
                                                              Atb, ideg_i, col_i, d_o, ce_i, rfull_i, rsub_i, csub_i);
    k_finalize<<<(N_NODES + 255) / 256, 256, 0, stream>>>(d_o, d_i, rfull_o, rsub_o, csub_o,
                                                          rfull_i, rsub_i, csub_i,
                                                          s_do, s_di, ro_s, co_s, ri_s, ci_s);
    // Pass A (csr_in): Ydst = 0.35*At_n@x - 0.15*mask-corr(SO_in);  z = At@(co_s*x)
    k_fused_pass<<<(N_NODES * 64) / 256, 256, 0, stream>>>(ideg_i, col_i, ce_i, xb, Ydst, zbuf,
                                                           s_di, s_do, ri_s, ci_s, co_s, d_i);
    // Pass B (csr_out, fused): Ysrc = 0.35*A_n@x + 0.15*ro_s*(A@z - corr);  z2 = A@(ci_s*x)
    k_pass_b<<<(N_NODES * 64) / 256, 256, 0, stream>>>(ideg_o, col_o, ce_o, xb, zbuf, Ysrc, z2buf,
                                                       s_do, s_di, ro_s, co_s, ci_s, d_o);
    // Pass C: Ydst += 0.15*ri_s*(At@z2)
    k_spmm_accum<<<(N_NODES * 64) / 256, 256, 0, stream>>>(ideg_i, col_i, z2buf, Ydst, ri_s);
    // Final GEMM halves then combine with bias
    k_sgemm2<<<dim3(N_NODES / 64, D_FEAT / 64, 2), 256, 0, stream>>>(Ysrc, Ydst, Ws, Wd, part0, part1);
    k_combine<<<(N_NODES * D_FEAT / 4) / 256, 256, 0, stream>>>((const float4*)part0, (const float4*)part1,
                                                                (const float4*)bs, (const float4*)bd,
                                                                (float4*)out);
}

// Round 8
// 172.055 us; speedup vs baseline: 2.1443x; 1.0053x over previous
//
#include <hip/hip_runtime.h>
#include <cstdint>
#include <cstddef>

#define N_NODES 4096
#define NWORDS  64          // 4096 bits / 64
#define E_EDGES 131072
#define D_FEAT  256
#define D4      (D_FEAT/4)  // 64 ushort4/float4 groups per row (4 feats per lane)
#define ELL     128         // fixed slots per node (Poisson(32) -> P(deg>128) ~ 1e-40)

typedef unsigned long long u64;

__device__ inline float bf2f(unsigned short u) {
    return __uint_as_float(((unsigned int)u) << 16);
}
__device__ inline unsigned short f2bf(float f) {   // round-to-nearest-even
    unsigned int u = __float_as_uint(f);
    return (unsigned short)((u + 0x7fffu + ((u >> 16) & 1u)) >> 16);
}

// ---------------------------------------------------------------- scatter + x->bf16 convert (disjoint block ranges)
__global__ __launch_bounds__(256) void k_scatter_cvt(const int* __restrict__ ei,
                                                     u64* __restrict__ Ab, u64* __restrict__ Atb,
                                                     const float* __restrict__ x, unsigned short* __restrict__ xb) {
    int b = blockIdx.x;
    if (b < E_EDGES / 256) {
        int e = b * 256 + threadIdx.x;
        int r = ei[e];
        int c = ei[E_EDGES + e];
        atomicOr(&Ab [(size_t)r * NWORDS + (c >> 6)], 1ull << (c & 63));
        atomicOr(&Atb[(size_t)c * NWORDS + (r >> 6)], 1ull << (r & 63));
    } else {
        int i = (b - E_EDGES / 256) * 256 + threadIdx.x;   // over N*D/4 groups
        float4 v = ((const float4*)x)[i];
        ushort4 q = { f2bf(v.x), f2bf(v.y), f2bf(v.z), f2bf(v.w) };
        ((ushort4*)xb)[i] = q;
    }
}

// ---------------------------------------------------------------- fill + degree + per-edge intersections (wave per node-dir)
// Extract ELL list (keep in LDS), write cols + degree, then common-neighbor
// counts over the LDS list: 16-lane groups, 4 edges in flight, lane s holds words 4s..4s+3.
__global__ __launch_bounds__(256) void k_fill_so(const u64* __restrict__ Ab,  int* __restrict__ col_o,
                                                 float* __restrict__ d_o, int* __restrict__ ideg_o,
                                                 float* __restrict__ ce_o, float* __restrict__ rsub_o, float* __restrict__ csub_o,
                                                 const u64* __restrict__ Atb, int* __restrict__ col_i,
                                                 float* __restrict__ d_i, int* __restrict__ ideg_i,
                                                 float* __restrict__ ce_i, float* __restrict__ rsub_i, float* __restrict__ csub_i) {
    __shared__ int lcol[4][ELL];
    int wslot = threadIdx.x >> 6;
    int gw   = (blockIdx.x * blockDim.x + threadIdx.x) >> 6;
    int lane = threadIdx.x & 63;
    if (gw >= 2 * N_NODES) return;
    int half = gw >= N_NODES;
    int wid  = half ? gw - N_NODES : gw;
    const u64* bits = half ? Atb : Ab;
    int*       cols = half ? col_i : col_o;
    float*     dd   = half ? d_i   : d_o;
    int*       idg  = half ? ideg_i : ideg_o;
    float*     ce   = half ? ce_i   : ce_o;
    float*     rsub = half ? rsub_i : rsub_o;
    float*     csub = half ? csub_i : csub_o;

    // --- extract list ---
    u64 wv = bits[(size_t)wid * NWORDS + lane];
    int cnt = __popcll(wv);
    int inc = cnt;
    for (int off = 1; off < 64; off <<= 1) {
        int t = __shfl_up(inc, off);
        if (lane >= off) inc += t;
    }
    int deg = __shfl(inc, 63);
    int pos = inc - cnt;                    // exclusive prefix within node
    u64 t = wv;
    int base = wid << 7;
    while (t) {
        int b = __builtin_ctzll(t);
        int c = lane * 64 + b;
        lcol[wslot][pos] = c;
        cols[base + pos] = c;
        ++pos;
        t &= t - 1;
    }
    if (lane == 63) { dd[wid] = (float)deg; idg[wid] = deg; }

    // --- intersections over own list (LDS) ---
    int g = lane >> 4, s = lane & 15;
    const u64* aw = &bits[(size_t)wid * NWORDS + s * 4];
    u64 a0 = aw[0], a1 = aw[1], a2 = aw[2], a3 = aw[3];
    float rs = 0.f;
    for (int p = g; p < deg; p += 4) {
        int j = lcol[wslot][p];
        const u64* bw = &bits[(size_t)j * NWORDS + s * 4];
        u64 b0 = bw[0], b1 = bw[1], b2 = bw[2], b3 = bw[3];
        int c = __popcll(a0 & b0) + __popcll(a1 & b1) + __popcll(a2 & b2) + __popcll(a3 & b3);
        c += __shfl_xor(c, 1);
        c += __shfl_xor(c, 2);
        c += __shfl_xor(c, 4);
        c += __shfl_xor(c, 8);
        if (s == 0) {
            float cf = (j == wid) ? 0.f : (float)c;   // self-loop handled by diag term
            ce[base + p] = cf;
            if (cf != 0.f) atomicAdd(&csub[j], cf);
            rs += cf;
        }
    }
    rs += __shfl_xor(rs, 16); rs += __shfl_xor(rs, 32);
    if (lane == 0) rsub[wid] = rs;
}

// ---------------------------------------------------------------- rfull gather + scales (wave per node-dir)
// half=0 (out-dir): rf = Sum_{j in succ(i)} d_i[j]; writes s_do, ro_s, co_s.
// half=1 (in-dir):  rf = Sum_{j in pred(i)} d_o[j]; writes s_di, ri_s, ci_s.
__global__ __launch_bounds__(256) void k_finalize2(const int* __restrict__ ideg_o, const int* __restrict__ col_o,
                                                   const float* __restrict__ d_o,
                                                   const int* __restrict__ ideg_i, const int* __restrict__ col_i,
                                                   const float* __restrict__ d_i,
                                                   const float* __restrict__ rsub_o, const float* __restrict__ csub_o,
                                                   const float* __restrict__ rsub_i, const float* __restrict__ csub_i,
                                                   float* __restrict__ s_do, float* __restrict__ s_di,
                                                   float* __restrict__ ro_s, float* __restrict__ co_s,
                                                   float* __restrict__ ri_s, float* __restrict__ ci_s) {
    int gw   = (blockIdx.x * blockDim.x + threadIdx.x) >> 6;
    int lane = threadIdx.x & 63;
    if (gw >= 2 * N_NODES) return;
    int half = gw >= N_NODES;
    int wid  = half ? gw - N_NODES : gw;
    const int*   cols = half ? col_i  : col_o;
    const int*   idg  = half ? ideg_i : ideg_o;
    const float* dcol = half ? d_o    : d_i;     // neighbor degree in the OTHER direction
    int deg = idg[wid];
    int base = wid << 7;
    float rf = 0.f;
    for (int l = lane; l < deg; l += 64) rf += dcol[cols[base + l]];
    for (int off = 32; off; off >>= 1) rf += __shfl_xor(rf, off);
    if (lane == 0) {
        float dself = (half ? d_i : d_o)[wid];
        float sd = dself > 0.f ? rsqrtf(dself) : 0.f;
        (half ? s_di : s_do)[wid] = sd;
        float rsv = (half ? rsub_i : rsub_o)[wid];
        float csv = (half ? csub_i : csub_o)[wid];
        float r_ = rf - dself - rsv;     // masked SO row sum
        float c_ = rf - dself - csv;     // masked SO col sum
        (half ? ri_s : ro_s)[wid] = r_ > 0.f ? rsqrtf(r_) : 0.f;
        (half ? ci_s : co_s)[wid] = c_ > 0.f ? rsqrtf(c_) : 0.f;
    }
}

// ---------------------------------------------------------------- pass A (csr_in): Ydst partial + z (bf16 out)
// Ydst[i] = 0.35*s_di[i]*Sum_j s_do[j]*x[j] - 0.15*ri_s[i]*( Sum_j ce*ci_s[j]*x[j] + d_i[i]*ci_s[i]*x[i] )
// z[i]    = Sum_j co_s[j]*x[j]      (stored bf16)
__global__ __launch_bounds__(256) void k_fused_pass(const int* __restrict__ idg, const int* __restrict__ cols,
                                                    const float* __restrict__ ce, const unsigned short* __restrict__ xb,
                                                    float* __restrict__ Y, unsigned short* __restrict__ zout,
                                                    const float* __restrict__ srow_fo, const float* __restrict__ scol_fo,
                                                    const float* __restrict__ srow_so, const float* __restrict__ scol_so,
                                                    const float* __restrict__ scol_z, const float* __restrict__ dself) {
    int wid  = (blockIdx.x * blockDim.x + threadIdx.x) >> 6;
    int lane = threadIdx.x & 63;
    if (wid >= N_NODES) return;
    const ushort4* x4 = (const ushort4*)xb;
    float4 a1 = {0,0,0,0}, a2 = {0,0,0,0}, az = {0,0,0,0};
    int p0 = wid << 7, p1 = p0 + idg[wid];
    int p = p0;
    for (; p + 4 <= p1; p += 4) {
        int j0 = cols[p], j1 = cols[p+1], j2 = cols[p+2], j3 = cols[p+3];
        ushort4 q0 = x4[(size_t)j0 * D4 + lane];
        ushort4 q1 = x4[(size_t)j1 * D4 + lane];
        ushort4 q2 = x4[(size_t)j2 * D4 + lane];
        ushort4 q3 = x4[(size_t)j3 * D4 + lane];
        float f0 = scol_fo[j0], f1 = scol_fo[j1], f2 = scol_fo[j2], f3 = scol_fo[j3];
        float s0 = ce[p]   * scol_so[j0];
        float s1 = ce[p+1] * scol_so[j1];
        float s2 = ce[p+2] * scol_so[j2];
        float s3 = ce[p+3] * scol_so[j3];
        float z0 = scol_z[j0], z1 = scol_z[j1], z2 = scol_z[j2], z3 = scol_z[j3];
        float v0x = bf2f(q0.x), v0y = bf2f(q0.y), v0z = bf2f(q0.z), v0w = bf2f(q0.w);
        float v1x = bf2f(q1.x), v1y = bf2f(q1.y), v1z = bf2f(q1.z), v1w = bf2f(q1.w);
        float v2x = bf2f(q2.x), v2y = bf2f(q2.y), v2z = bf2f(q2.z), v2w = bf2f(q2.w);
        float v3x = bf2f(q3.x), v3y = bf2f(q3.y), v3z = bf2f(q3.z), v3w = bf2f(q3.w);
        a1.x += f0*v0x + f1*v1x + f2*v2x + f3*v3x;
        a1.y += f0*v0y + f1*v1y + f2*v2y + f3*v3y;
        a1.z += f0*v0z + f1*v1z + f2*v2z + f3*v3z;
        a1.w += f0*v0w + f1*v1w + f2*v2w + f3*v3w;
        a2.x += s0*v0x + s1*v1x + s2*v2x + s3*v3x;
        a2.y += s0*v0y + s1*v1y + s2*v2y + s3*v3y;
        a2.z += s0*v0z + s1*v1z + s2*v2z + s3*v3z;
        a2.w += s0*v0w + s1*v1w + s2*v2w + s3*v3w;
        az.x += z0*v0x + z1*v1x + z2*v2x + z3*v3x;
        az.y += z0*v0y + z1*v1y + z2*v2y + z3*v3y;
        az.z += z0*v0z + z1*v1z + z2*v2z + z3*v3z;
        az.w += z0*v0w + z1*v1w + z2*v2w + z3*v3w;
    }
    for (; p < p1; ++p) {
        int j = cols[p];
        float w1 = scol_fo[j];
        float w2 = ce[p] * scol_so[j];
        float wz = scol_z[j];
        ushort4 q = x4[(size_t)j * D4 + lane];
        float vx = bf2f(q.x), vy = bf2f(q.y), vz = bf2f(q.z), vw = bf2f(q.w);
        a1.x += w1 * vx; a1.y += w1 * vy; a1.z += w1 * vz; a1.w += w1 * vw;
        a2.x += w2 * vx; a2.y += w2 * vy; a2.z += w2 * vz; a2.w += w2 * vw;
        az.x += wz * vx; az.y += wz * vy; az.z += wz * vz; az.w += wz * vw;
    }
    float wd = dself[wid] * scol_so[wid];
    ushort4 qi = x4[(size_t)wid * D4 + lane];
    a2.x += wd * bf2f(qi.x); a2.y += wd * bf2f(qi.y); a2.z += wd * bf2f(qi.z); a2.w += wd * bf2f(qi.w);
    float c1 = 0.35f * srow_fo[wid];
    float c2 = -0.15f * srow_so[wid];
    float4 r;
    r.x = c1 * a1.x + c2 * a2.x;
    r.y = c1 * a1.y + c2 * a2.y;
    r.z = c1 * a1.z + c2 * a2.z;
    r.w = c1 * a1.w + c2 * a2.w;
    ((float4*)Y)[(size_t)wid * D4 + lane] = r;
    ushort4 zq = { f2bf(az.x), f2bf(az.y), f2bf(az.z), f2bf(az.w) };
    ((ushort4*)zout)[(size_t)wid * D4 + lane] = zq;
}

// ---------------------------------------------------------------- pass B (csr_out, fused): full Ysrc + z2 (bf16 in/out)
// Ysrc[i] = 0.35*s_do[i]*Sum_j s_di[j]*x[j]
//         + 0.15*ro_s[i]*( Sum_j z[j] - Sum_j ce*co_s[j]*x[j] - d_o[i]*co_s[i]*x[i] )
// z2[i]   = Sum_j ci_s[j]*x[j]      (stored bf16)
__global__ __launch_bounds__(256) void k_pass_b(const int* __restrict__ idg, const int* __restrict__ cols,
                                                const float* __restrict__ ce, const unsigned short* __restrict__ xb,
                                                const unsigned short* __restrict__ zin,
                                                float* __restrict__ Y, unsigned short* __restrict__ z2out,
                                                const float* __restrict__ s_do, const float* __restrict__ s_di,
                                                const float* __restrict__ ro_s, const float* __restrict__ co_s,
                                                const float* __restrict__ ci_s, const float* __restrict__ d_o) {
    int wid  = (blockIdx.x * blockDim.x + threadIdx.x) >> 6;
    int lane = threadIdx.x & 63;
    if (wid >= N_NODES) return;
    const ushort4* x4 = (const ushort4*)xb;
    const ushort4* z4 = (const ushort4*)zin;
    float4 a1 = {0,0,0,0}, a2 = {0,0,0,0}, az = {0,0,0,0}, a3 = {0,0,0,0};
    int p0 = wid << 7, p1 = p0 + idg[wid];
    int p = p0;
    for (; p + 2 <= p1; p += 2) {
        int j0 = cols[p], j1 = cols[p+1];
        ushort4 q0 = x4[(size_t)j0 * D4 + lane];
        ushort4 q1 = x4[(size_t)j1 * D4 + lane];
        ushort4 u0 = z4[(size_t)j0 * D4 + lane];
        ushort4 u1 = z4[(size_t)j1 * D4 + lane];
        float f0 = s_di[j0], f1 = s_di[j1];
        float s0 = ce[p]   * co_s[j0];
        float s1 = ce[p+1] * co_s[j1];
        float w0 = ci_s[j0], w1 = ci_s[j1];
        float v0x = bf2f(q0.x), v0y = bf2f(q0.y), v0z = bf2f(q0.z), v0w = bf2f(q0.w);
        float v1x = bf2f(q1.x), v1y = bf2f(q1.y), v1z = bf2f(q1.z), v1w = bf2f(q1.w);
        a1.x += f0*v0x + f1*v1x;  a1.y += f0*v0y + f1*v1y;
        a1.z += f0*v0z + f1*v1z;  a1.w += f0*v0w + f1*v1w;
        a2.x += s0*v0x + s1*v1x;  a2.y += s0*v0y + s1*v1y;
        a2.z += s0*v0z + s1*v1z;  a2.w += s0*v0w + s1*v1w;
        az.x += w0*v0x + w1*v1x;  az.y += w0*v0y + w1*v1y;
        az.z += w0*v0z + w1*v1z;  az.w += w0*v0w + w1*v1w;
        a3.x += bf2f(u0.x) + bf2f(u1.x);  a3.y += bf2f(u0.y) + bf2f(u1.y);
        a3.z += bf2f(u0.z) + bf2f(u1.z);  a3.w += bf2f(u0.w) + bf2f(u1.w);
    }
    for (; p < p1; ++p) {
        int j = cols[p];
        ushort4 q = x4[(size_t)j * D4 + lane];
        ushort4 u = z4[(size_t)j * D4 + lane];
        float w1 = s_di[j];
        float w2 = ce[p] * co_s[j];
        float wz = ci_s[j];
        float vx = bf2f(q.x), vy = bf2f(q.y), vz = bf2f(q.z), vw = bf2f(q.w);
        a1.x += w1 * vx; a1.y += w1 * vy; a1.z += w1 * vz; a1.w += w1 * vw;
        a2.x += w2 * vx; a2.y += w2 * vy; a2.z += w2 * vz; a2.w += w2 * vw;
        az.x += wz * vx; az.y += wz * vy; az.z += wz * vz; az.w += wz * vw;
        a3.x += bf2f(u.x); a3.y += bf2f(u.y); a3.z += bf2f(u.z); a3.w += bf2f(u.w);
    }
    float wd = d_o[wid] * co_s[wid];
    ushort4 qi = x4[(size_t)wid * D4 + lane];
    a2.x += wd * bf2f(qi.x); a2.y += wd * bf2f(qi.y); a2.z += wd * bf2f(qi.z); a2.w += wd * bf2f(qi.w);
    float c1 = 0.35f * s_do[wid];
    float c2 = 0.15f * ro_s[wid];
    float4 r;
    r.x = c1 * a1.x + c2 * (a3.x - a2.x);
    r.y = c1 * a1.y + c2 * (a3.y - a2.y);
    r.z = c1 * a1.z + c2 * (a3.z - a2.z);
    r.w = c1 * a1.w + c2 * (a3.w - a2.w);
    ((float4*)Y)[(size_t)wid * D4 + lane] = r;
    ushort4 zq = { f2bf(az.x), f2bf(az.y), f2bf(az.z), f2bf(az.w) };
    ((ushort4*)z2out)[(size_t)wid * D4 + lane] = zq;
}

// ---------------------------------------------------------------- pass C: Y[i] += 0.15*srow[i]*Sum_j z2[j]  (bf16 gather)
__global__ __launch_bounds__(256) void k_spmm_accum(const int* __restrict__ idg, const int* __restrict__ cols,
                                                    const unsigned short* __restrict__ zin, float* __restrict__ Y,
                                                    const float* __restrict__ srow) {
    int wid  = (blockIdx.x * blockDim.x + threadIdx.x) >> 6;
    int lane = threadIdx.x & 63;
    if (wid >= N_NODES) return;
    const ushort4* z4 = (const ushort4*)zin;
    float4 a = {0,0,0,0};
    int p0 = wid << 7, p1 = p0 + idg[wid];
    int p = p0;
    for (; p + 4 <= p1; p += 4) {
        int j0 = cols[p], j1 = cols[p+1], j2 = cols[p+2], j3 = cols[p+3];
        ushort4 v0 = z4[(size_t)j0 * D4 + lane];
        ushort4 v1 = z4[(size_t)j1 * D4 + lane];
        ushort4 v2 = z4[(size_t)j2 * D4 + lane];
        ushort4 v3 = z4[(size_t)j3 * D4 + lane];
        a.x += bf2f(v0.x) + bf2f(v1.x) + bf2f(v2.x) + bf2f(v3.x);
        a.y += bf2f(v0.y) + bf2f(v1.y) + bf2f(v2.y) + bf2f(v3.y);
        a.z += bf2f(v0.z) + bf2f(v1.z) + bf2f(v2.z) + bf2f(v3.z);
        a.w += bf2f(v0.w) + bf2f(v1.w) + bf2f(v2.w) + bf2f(v3.w);
    }
    for (; p < p1; ++p) {
        int j = cols[p];
        ushort4 v = z4[(size_t)j * D4 + lane];
        a.x += bf2f(v.x); a.y += bf2f(v.y); a.z += bf2f(v.z); a.w += bf2f(v.w);
    }
    float s = 0.15f * srow[wid];
    float4* y4 = (float4*)Y;
    float4 cur = y4[(size_t)wid * D4 + lane];
    cur.x += s * a.x; cur.y += s * a.y; cur.z += s * a.z; cur.w += s * a.w;
    y4[(size_t)wid * D4 + lane] = cur;
}

// ---------------------------------------------------------------- final GEMM, both halves: out = Ysrc@Ws^T + Ydst@Wd^T + 0.5*(bs+bd)
// K-major LDS tiles, stride 68 floats (conflict-free b128 fragment reads)
__global__ __launch_bounds__(256) void k_sgemm_both(const float* __restrict__ Ysrc, const float* __restrict__ Ydst,
                                                    const float* __restrict__ Ws, const float* __restrict__ Wd,
                                                    const float* __restrict__ bsrc, const float* __restrict__ bdst,
                                                    float* __restrict__ out) {
    __shared__ float As[32][68];
    __shared__ float Bs[32][68];
    int tid = threadIdx.x;
    int tx = tid & 15, ty = tid >> 4;          // 16x16 threads, 4x4 outputs each
    int row0 = blockIdx.x * 64;
    int col0 = blockIdx.y * 64;
    int lr = tid >> 2;
    int lc = (tid & 3) * 8;
    float acc[4][4] = {};
    for (int half = 0; half < 2; ++half) {
        const float* Y = half ? Ydst : Ysrc;
        const float* W = half ? Wd : Ws;
        for (int k0 = 0; k0 < 256; k0 += 32) {
            float4 a0 = *(const float4*)&Y[(size_t)(row0 + lr) * 256 + k0 + lc];
            float4 a1 = *(const float4*)&Y[(size_t)(row0 + lr) * 256 + k0 + lc + 4];
            float4 b0 = *(const float4*)&W[(size_t)(col0 + lr) * 256 + k0 + lc];
            float4 b1 = *(const float4*)&W[(size_t)(col0 + lr) * 256 + k0 + lc + 4];
            __syncthreads();
            As[lc+0][lr] = a0.x; As[lc+1][lr] = a0.y; As[lc+2][lr] = a0.z; As[lc+3][lr] = a0.w;
            As[lc+4][lr] = a1.x; As[lc+5][lr] = a1.y; As[lc+6][lr] = a1.z; As[lc+7][lr] = a1.w;
            Bs[lc+0][lr] = b0.x; Bs[lc+1][lr] = b0.y; Bs[lc+2][lr] = b0.z; Bs[lc+3][lr] = b0.w;
            Bs[lc+4][lr] = b1.x; Bs[lc+5][lr] = b1.y; Bs[lc+6][lr] = b1.z; Bs[lc+7][lr] = b1.w;
            __syncthreads();
#pragma unroll
            for (int kk = 0; kk < 32; ++kk) {
                float4 av = *(const float4*)&As[kk][ty * 4];
                float4 bv = *(const float4*)&Bs[kk][tx * 4];
                acc[0][0] += av.x * bv.x; acc[0][1] += av.x * bv.y; acc[0][2] += av.x * bv.z; acc[0][3] += av.x * bv.w;
                acc[1][0] += av.y * bv.x; acc[1][1] += av.y * bv.y; acc[1][2] += av.y * bv.z; acc[1][3] += av.y * bv.w;
                acc[2][0] += av.z * bv.x; acc[2][1] += av.z * bv.y; acc[2][2] += av.z * bv.z; acc[2][3] += av.z * bv.w;
                acc[3][0] += av.w * bv.x; acc[3][1] += av.w * bv.y; acc[3][2] += av.w * bv.z; acc[3][3] += av.w * bv.w;
            }
        }
    }
#pragma unroll
    for (int r = 0; r < 4; ++r) {
        int orow = row0 + ty * 4 + r;
#pragma unroll
        for (int c = 0; c < 4; ++c) {
            int ocol = col0 + tx * 4 + c;
            out[(size_t)orow * 256 + ocol] = acc[r][c] + 0.5f * (bsrc[ocol] + bdst[ocol]);
        }
    }
}

// ---------------------------------------------------------------- launch
extern "C" void kernel_launch(void* const* d_in, const int* in_sizes, int n_in,
                              void* d_out, int out_size, void* d_ws, size_t ws_size,
                              hipStream_t stream) {
    const float* x  = (const float*)d_in[0];
    const int*   ei = (const int*)  d_in[1];
    const float* Ws = (const float*)d_in[2];
    const float* bs = (const float*)d_in[3];
    const float* Wd = (const float*)d_in[4];
    const float* bd = (const float*)d_in[5];
    float* out = (float*)d_out;

    char* ws = (char*)d_ws;
    size_t off = 0;
    auto alloc = [&](size_t bytes) -> void* {
        void* p = ws + off;
        off = (off + bytes + 255) & ~(size_t)255;
        return p;
    };
    // Keep Ab|Atb|csub_o|csub_i contiguous: zeroed by ONE memset.
    u64*   Ab      = (u64*)  alloc((size_t)N_NODES * NWORDS * 8);   // 2 MB
    u64*   Atb     = (u64*)  alloc((size_t)N_NODES * NWORDS * 8);   // 2 MB
    float* csub_o  = (float*)alloc(N_NODES * 4);
    float* csub_i  = (float*)alloc(N_NODES * 4);
    unsigned short* xb = (unsigned short*)alloc((size_t)N_NODES * D_FEAT * 2);   // 2 MB bf16
    float* d_o     = (float*)alloc(N_NODES * 4);
    float* d_i     = (float*)alloc(N_NODES * 4);
    int*   ideg_o  = (int*)  alloc(N_NODES * 4);
    int*   ideg_i  = (int*)  alloc(N_NODES * 4);
    int*   col_o   = (int*)  alloc((size_t)N_NODES * ELL * 4);      // 2 MB
    int*   col_i   = (int*)  alloc((size_t)N_NODES * ELL * 4);      // 2 MB
    float* ce_o    = (float*)alloc((size_t)N_NODES * ELL * 4);      // 2 MB
    float* ce_i    = (float*)alloc((size_t)N_NODES * ELL * 4);      // 2 MB
    float* rsub_o  = (float*)alloc(N_NODES * 4);
    float* rsub_i  = (float*)alloc(N_NODES * 4);
    float* s_do    = (float*)alloc(N_NODES * 4);
    float* s_di    = (float*)alloc(N_NODES * 4);
    float* ro_s    = (float*)alloc(N_NODES * 4);
    float* co_s    = (float*)alloc(N_NODES * 4);
    float* ri_s    = (float*)alloc(N_NODES * 4);
    float* ci_s    = (float*)alloc(N_NODES * 4);
    unsigned short* zbuf  = (unsigned short*)alloc((size_t)N_NODES * D_FEAT * 2);  // 2 MB bf16
    unsigned short* z2buf = (unsigned short*)alloc((size_t)N_NODES * D_FEAT * 2);  // 2 MB bf16
    float* Ysrc    = (float*)alloc((size_t)N_NODES * D_FEAT * 4);   // 4 MB
    float* Ydst    = (float*)alloc((size_t)N_NODES * D_FEAT * 4);   // 4 MB

    // single zero-fill: Ab + Atb + csub_o + csub_i (contiguous)
    hipMemsetAsync(Ab, 0, (size_t)N_NODES * NWORDS * 8 * 2 + (size_t)N_NODES * 4 * 2, stream);

    // scatter (512 blocks) + x->bf16 convert (1024 blocks)
    k_scatter_cvt<<<E_EDGES / 256 + (N_NODES * D_FEAT / 4) / 256, 256, 0, stream>>>(ei, Ab, Atb, x, xb);
    // fill + degree + intersections (both directions)
    k_fill_so<<<(2 * N_NODES * 64) / 256, 256, 0, stream>>>(Ab,  col_o, d_o, ideg_o, ce_o, rsub_o, csub_o,
                                                            Atb, col_i, d_i, ideg_i, ce_i, rsub_i, csub_i);
    // rfull gather + scales
    k_finalize2<<<(2 * N_NODES * 64) / 256, 256, 0, stream>>>(ideg_o, col_o, d_o, ideg_i, col_i, d_i,
                                                              rsub_o, csub_o, rsub_i, csub_i,
                                                              s_do, s_di, ro_s, co_s, ri_s, ci_s);
    // Pass A (csr_in): Ydst = 0.35*At_n@x - 0.15*mask-corr(SO_in);  z = At@(co_s*x)
    k_fused_pass<<<(N_NODES * 64) / 256, 256, 0, stream>>>(ideg_i, col_i, ce_i, xb, Ydst, zbuf,
                                                           s_di, s_do, ri_s, ci_s, co_s, d_i);
    // Pass B (csr_out, fused): Ysrc = 0.35*A_n@x + 0.15*ro_s*(A@z - corr);  z2 = A@(ci_s*x)
    k_pass_b<<<(N_NODES * 64) / 256, 256, 0, stream>>>(ideg_o, col_o, ce_o, xb, zbuf, Ysrc, z2buf,
                                                       s_do, s_di, ro_s, co_s, ci_s, d_o);
    // Pass C: Ydst += 0.15*ri_s*(At@z2)
    k_spmm_accum<<<(N_NODES * 64) / 256, 256, 0, stream>>>(ideg_i, col_i, z2buf, Ydst, ri_s);
    // Final GEMM (both halves) + bias, direct to out
    k_sgemm_both<<<dim3(N_NODES / 64, D_FEAT / 64), 256, 0, stream>>>(Ysrc, Ydst, Ws, Wd, bs, bd, out);
}